// Round 1
// baseline (3056.328 us; speedup 1.0000x reference)
//
#include <hip/hip_runtime.h>
#include <hip/hip_bf16.h>
#include <math.h>

// Problem constants
#define B    2
#define CIN  64
#define LIN  8192
#define L    2048
#define D    128
#define DI   256
#define NS   16
#define RK   8
#define NSTREAM 4   // (dir, batch): s = dir*2 + b
#define TT   8      // token tile for GEMM-ish kernels

__device__ __forceinline__ float sigmoidf_(float x){ return 1.f/(1.f+__expf(-x)); }
__device__ __forceinline__ float siluf_(float x){ return x*sigmoidf_(x); }

// ---------------- downsample conv (stride 4, VALID) + silu, write fwd + reversed bwd copies
__global__ void k_downsample(const float* __restrict__ x, const float* __restrict__ w,
                             const float* __restrict__ bias, float* __restrict__ h){
    // grid (L, B), block 128 (d)
    int l = blockIdx.x, b = blockIdx.y, d = threadIdx.x;
    __shared__ float xs[CIN*4];
    for (int i = d; i < CIN*4; i += 128){
        int c = i >> 2, k = i & 3;
        xs[i] = x[(b*CIN + c)*LIN + 4*l + k];
    }
    __syncthreads();
    const float* wd = w + d*CIN*4;   // (COUT, CIN, K) row-major; index c*4+k matches xs
    float acc = 0.f;
    #pragma unroll 8
    for (int i = 0; i < CIN*4; ++i) acc += xs[i]*wd[i];
    float v = siluf_(acc + bias[d]);
    h[(b*L + l)*D + d] = v;                        // fwd streams s=b
    h[((2+b)*L + (L-1-l))*D + d] = v;              // bwd streams s=2+b (reversed)
}

// ---------------- residual update + layernorm
__global__ void k_resln(const float* __restrict__ curIn, float* __restrict__ res,
                        const float* __restrict__ lnw, const float* __restrict__ lnb,
                        float* __restrict__ hn, int blk, int first){
    // grid (L, 4), block 128
    int l = blockIdx.x, s = blockIdx.y, d = threadIdx.x;
    int j = (s>>1)*3 + blk;
    int tb = s*L + l;
    float r = curIn[tb*D + d];
    if (!first) r += res[tb*D + d];
    res[tb*D + d] = r;
    __shared__ float red[128];
    red[d] = r; __syncthreads();
    for (int off=64; off; off>>=1){ if (d<off) red[d]+=red[d+off]; __syncthreads(); }
    float mean = red[0]*(1.f/128.f);
    __syncthreads();
    float c = r - mean;
    red[d] = c*c; __syncthreads();
    for (int off=64; off; off>>=1){ if (d<off) red[d]+=red[d+off]; __syncthreads(); }
    float var = red[0]*(1.f/128.f);
    float rstd = rsqrtf(var + 1e-5f);
    hn[tb*D + d] = c*rstd*lnw[j*D + d] + lnb[j*D + d];
}

// ---------------- in_proj: xz = hn @ W^T, split into xm / z
__global__ void k_inproj(const float* __restrict__ hn, const float* __restrict__ W,
                         float* __restrict__ xm, float* __restrict__ z, int blk){
    // grid (L/TT, 2, 4), block 256 (e within half)
    int s = blockIdx.z; int j = (s>>1)*3 + blk;
    int l0 = blockIdx.x*TT;
    int e = blockIdx.y*256 + threadIdx.x;
    __shared__ float xs[TT][D];
    int tb0 = s*L + l0;
    for (int i = threadIdx.x; i < TT*D; i += 256){
        int t = i >> 7, dd = i & 127;
        xs[t][dd] = hn[(tb0+t)*D + dd];
    }
    __syncthreads();
    const float* wr = W + (j*2*DI + e)*D;
    float acc[TT];
    #pragma unroll
    for (int t=0;t<TT;++t) acc[t]=0.f;
    for (int dd=0; dd<D; ++dd){
        float wv = wr[dd];
        #pragma unroll
        for (int t=0;t<TT;++t) acc[t] += xs[t][dd]*wv;
    }
    if (e < DI){
        #pragma unroll
        for (int t=0;t<TT;++t) xm[(tb0+t)*DI + e] = acc[t];
    } else {
        int e2 = e - DI;
        #pragma unroll
        for (int t=0;t<TT;++t) z[(tb0+t)*DI + e2] = acc[t];
    }
}

// ---------------- causal depthwise conv width 4 + bias + silu
__global__ void k_conv(const float* __restrict__ xm, const float* __restrict__ cw,
                       const float* __restrict__ cb, float* __restrict__ xc, int blk){
    // grid (L, 4), block 256
    int s = blockIdx.y; int j = (s>>1)*3 + blk;
    int l = blockIdx.x; int e = threadIdx.x;
    int sb = s*L;
    const float* w = cw + (j*DI + e)*4;
    float acc = cb[j*DI + e];
    #pragma unroll
    for (int k=0;k<4;++k){
        int ll = l + k - 3;
        if (ll >= 0) acc += xm[(sb+ll)*DI + e]*w[k];
    }
    xc[(sb+l)*DI + e] = siluf_(acc);
}

// ---------------- x_proj: dbc = xc @ W^T (40 outputs), split dt_raw / Bc / Cc
__global__ void k_xproj(const float* __restrict__ xc, const float* __restrict__ W,
                        float* __restrict__ dtr, float* __restrict__ Bc,
                        float* __restrict__ Cc, int blk){
    // grid (L/4, 4), block 256 = 4 tokens x 64 lanes
    int s = blockIdx.y; int j = (s>>1)*3 + blk;
    int t = threadIdx.x >> 6;
    int lane = threadIdx.x & 63;
    int l = blockIdx.x*4 + t;
    int tb = s*L + l;
    __shared__ float xs[4][DI];
    for (int i = lane; i < DI; i += 64) xs[t][i] = xc[tb*DI + i];
    __syncthreads();
    if (lane < 40){
        const float* wr = W + (j*40 + lane)*DI;
        float acc = 0.f;
        #pragma unroll 8
        for (int e=0;e<DI;++e) acc += xs[t][e]*wr[e];
        if (lane < 8)       dtr[tb*RK + lane] = acc;
        else if (lane < 24) Bc[tb*NS + (lane-8)] = acc;
        else                Cc[tb*NS + (lane-24)] = acc;
    }
}

// ---------------- dt_proj + softplus
__global__ void k_dtproj(const float* __restrict__ dtr, const float* __restrict__ Wdt,
                         const float* __restrict__ bdt, float* __restrict__ dt, int blk){
    // grid (L/TT, 4), block 256 (e)
    int s = blockIdx.y; int j = (s>>1)*3 + blk;
    int l0 = blockIdx.x*TT;
    int e = threadIdx.x;
    __shared__ float rs[TT][RK];
    int tb0 = s*L + l0;
    for (int i = threadIdx.x; i < TT*RK; i += 256)
        rs[i>>3][i&7] = dtr[(tb0 + (i>>3))*RK + (i&7)];
    __syncthreads();
    const float* wr = Wdt + (j*DI + e)*RK;
    float wv[RK];
    #pragma unroll
    for (int r=0;r<RK;++r) wv[r] = wr[r];
    float bb = bdt[j*DI + e];
    for (int t=0;t<TT;++t){
        float acc = bb;
        #pragma unroll
        for (int r=0;r<RK;++r) acc += rs[t][r]*wv[r];
        dt[(tb0+t)*DI + e] = (acc > 20.f) ? acc : log1pf(__expf(acc));
    }
}

// ---------------- sequential SSM scan: thread per (d,n), 16-lane reduce for y
__global__ void k_scan(const float* __restrict__ dt, const float* __restrict__ xcv,
                       const float* __restrict__ Bc, const float* __restrict__ Cc,
                       const float* __restrict__ A_log, float* __restrict__ y, int blk){
    // grid (16, 4), block 256
    int s = blockIdx.y; int j = (s>>1)*3 + blk;
    int tid = threadIdx.x;
    int dl = tid >> 4, n = tid & 15;
    int d = blockIdx.x*16 + dl;
    float A = -__expf(A_log[(j*DI + d)*NS + n]);
    float hstate = 0.f;
    int sb = s*L;
    for (int l=0; l<L; ++l){
        int tb = sb + l;
        float dtv = dt[tb*DI + d];
        float xv  = xcv[tb*DI + d];
        float bv  = Bc[tb*NS + n];
        float cv  = Cc[tb*NS + n];
        float dA  = __expf(dtv*A);
        hstate = dA*hstate + dtv*bv*xv;
        float p = hstate*cv;
        p += __shfl_xor(p, 1, 16);
        p += __shfl_xor(p, 2, 16);
        p += __shfl_xor(p, 4, 16);
        p += __shfl_xor(p, 8, 16);
        if (n == 0) y[tb*DI + d] = p;
    }
}

// ---------------- fused gate + out_proj
__global__ void k_outproj(const float* __restrict__ y, const float* __restrict__ xcv,
                          const float* __restrict__ z, const float* __restrict__ Dp,
                          const float* __restrict__ W, float* __restrict__ cur, int blk){
    // grid (L/TT, 4), block 128 (dout)
    int s = blockIdx.y; int j = (s>>1)*3 + blk;
    int l0 = blockIdx.x*TT;
    int dout = threadIdx.x;
    __shared__ float ys[TT][DI];
    int tb0 = s*L + l0;
    const float* Dpj = Dp + j*DI;
    for (int i = threadIdx.x; i < TT*DI; i += 128){
        int t = i >> 8, e = i & 255;
        int a = (tb0+t)*DI + e;
        ys[t][e] = (y[a] + Dpj[e]*xcv[a]) * siluf_(z[a]);
    }
    __syncthreads();
    const float* wr = W + (j*D + dout)*DI;
    float acc[TT];
    #pragma unroll
    for (int t=0;t<TT;++t) acc[t]=0.f;
    for (int e=0;e<DI;++e){
        float wv = wr[e];
        #pragma unroll
        for (int t=0;t<TT;++t) acc[t] += ys[t][e]*wv;
    }
    #pragma unroll
    for (int t=0;t<TT;++t) cur[(tb0+t)*D + dout] = acc[t];
}

// ---------------- final combine: out0 (B,D,L), rf (B,L,D), rb (B,L,D reversed-domain)
__global__ void k_final(const float* __restrict__ cur, const float* __restrict__ res,
                        float* __restrict__ out){
    // grid (L, B), block 128
    int l = blockIdx.x, b = blockIdx.y, d = threadIdx.x;
    int tf = (b*L + l)*D + d;
    int tbk = ((2+b)*L + (L-1-l))*D + d;   // bwd at reversed index
    float f  = cur[tf] + res[tf];
    float bw = cur[tbk] + res[tbk];
    out[(b*D + d)*L + l] = f + bw;                               // out0 (2,128,2048)
    out[2*D*L + (b*L + l)*D + d] = res[tf];                      // rf
    out[2*D*L + 2*L*D + ((2+b)*L + l)*D - 2*L*D + d] = res[((2+b)*L + l)*D + d]; // rb
}

extern "C" void kernel_launch(void* const* d_in, const int* in_sizes, int n_in,
                              void* d_out, int out_size, void* d_ws, size_t ws_size,
                              hipStream_t stream){
    const float* x         = (const float*)d_in[0];
    const float* convd_w   = (const float*)d_in[1];
    const float* convd_b   = (const float*)d_in[2];
    const float* ln_w      = (const float*)d_in[3];
    const float* ln_b      = (const float*)d_in[4];
    const float* in_proj_w = (const float*)d_in[5];
    const float* conv_w    = (const float*)d_in[6];
    const float* conv_b    = (const float*)d_in[7];
    const float* xproj_w   = (const float*)d_in[8];
    const float* dtproj_w  = (const float*)d_in[9];
    const float* dtproj_b  = (const float*)d_in[10];
    const float* A_log     = (const float*)d_in[11];
    const float* Dparam    = (const float*)d_in[12];
    const float* outproj_w = (const float*)d_in[13];

    float* ws = (float*)d_ws;
    const size_t SZ_D  = (size_t)NSTREAM*L*D;    // 1,048,576
    const size_t SZ_DI = (size_t)NSTREAM*L*DI;   // 2,097,152
    float* h   = ws;            ws += SZ_D;
    float* res = ws;            ws += SZ_D;
    float* cur = ws;            ws += SZ_D;
    float* hn  = ws;            ws += SZ_D;
    float* xm  = ws;            ws += SZ_DI;
    float* z   = ws;            ws += SZ_DI;
    float* xc  = ws;            ws += SZ_DI;
    float* dt  = ws;            ws += SZ_DI;
    float* y   = ws;            ws += SZ_DI;
    float* dtr = ws;            ws += (size_t)NSTREAM*L*RK;
    float* Bc  = ws;            ws += (size_t)NSTREAM*L*NS;
    float* Cc  = ws;            ws += (size_t)NSTREAM*L*NS;

    k_downsample<<<dim3(L,B), 128, 0, stream>>>(x, convd_w, convd_b, h);

    for (int blk = 0; blk < 3; ++blk){
        k_resln<<<dim3(L,NSTREAM), 128, 0, stream>>>(blk==0 ? h : cur, res, ln_w, ln_b, hn, blk, blk==0);
        k_inproj<<<dim3(L/TT,2,NSTREAM), 256, 0, stream>>>(hn, in_proj_w, xm, z, blk);
        k_conv<<<dim3(L,NSTREAM), 256, 0, stream>>>(xm, conv_w, conv_b, xc, blk);
        k_xproj<<<dim3(L/4,NSTREAM), 256, 0, stream>>>(xc, xproj_w, dtr, Bc, Cc, blk);
        k_dtproj<<<dim3(L/TT,NSTREAM), 256, 0, stream>>>(dtr, dtproj_w, dtproj_b, dt, blk);
        k_scan<<<dim3(16,NSTREAM), 256, 0, stream>>>(dt, xc, Bc, Cc, A_log, y, blk);
        k_outproj<<<dim3(L/TT,NSTREAM), 128, 0, stream>>>(y, xc, z, Dparam, outproj_w, cur, blk);
    }

    k_final<<<dim3(L,B), 128, 0, stream>>>(cur, res, (float*)d_out);
}

// Round 2
// 722.388 us; speedup vs baseline: 4.2309x; 4.2309x over previous
//
#include <hip/hip_runtime.h>
#include <hip/hip_bf16.h>
#include <math.h>

// Problem constants
#define B    2
#define CIN  64
#define LIN  8192
#define L    2048
#define D    128
#define DI   256
#define NS   16
#define RK   8
#define NSTREAM 4   // (dir, batch): s = dir*2 + b
#define TT   8      // token tile for GEMM-ish kernels
#define CHUNK 64    // scan chunk length
#define NC   (L/CHUNK)  // 32 chunks

__device__ __forceinline__ float sigmoidf_(float x){ return 1.f/(1.f+__expf(-x)); }
__device__ __forceinline__ float siluf_(float x){ return x*sigmoidf_(x); }

// ---------------- downsample conv (stride 4, VALID) + silu, write fwd + reversed bwd copies
__global__ void k_downsample(const float* __restrict__ x, const float* __restrict__ w,
                             const float* __restrict__ bias, float* __restrict__ h){
    // grid (L, B), block 128 (d)
    int l = blockIdx.x, b = blockIdx.y, d = threadIdx.x;
    __shared__ float xs[CIN*4];
    for (int i = d; i < CIN*4; i += 128){
        int c = i >> 2, k = i & 3;
        xs[i] = x[(b*CIN + c)*LIN + 4*l + k];
    }
    __syncthreads();
    const float* wd = w + d*CIN*4;   // (COUT, CIN, K) row-major; index c*4+k matches xs
    float acc = 0.f;
    #pragma unroll 8
    for (int i = 0; i < CIN*4; ++i) acc += xs[i]*wd[i];
    float v = siluf_(acc + bias[d]);
    h[(b*L + l)*D + d] = v;                        // fwd streams s=b
    h[((2+b)*L + (L-1-l))*D + d] = v;              // bwd streams s=2+b (reversed)
}

// ---------------- residual update + layernorm
__global__ void k_resln(const float* __restrict__ curIn, float* __restrict__ res,
                        const float* __restrict__ lnw, const float* __restrict__ lnb,
                        float* __restrict__ hn, int blk, int first){
    // grid (L, 4), block 128
    int l = blockIdx.x, s = blockIdx.y, d = threadIdx.x;
    int j = (s>>1)*3 + blk;
    int tb = s*L + l;
    float r = curIn[tb*D + d];
    if (!first) r += res[tb*D + d];
    res[tb*D + d] = r;
    __shared__ float red[128];
    red[d] = r; __syncthreads();
    for (int off=64; off; off>>=1){ if (d<off) red[d]+=red[d+off]; __syncthreads(); }
    float mean = red[0]*(1.f/128.f);
    __syncthreads();
    float c = r - mean;
    red[d] = c*c; __syncthreads();
    for (int off=64; off; off>>=1){ if (d<off) red[d]+=red[d+off]; __syncthreads(); }
    float var = red[0]*(1.f/128.f);
    float rstd = rsqrtf(var + 1e-5f);
    hn[tb*D + d] = c*rstd*lnw[j*D + d] + lnb[j*D + d];
}

// ---------------- in_proj: xz = hn @ W^T, split into xm / z
__global__ void k_inproj(const float* __restrict__ hn, const float* __restrict__ W,
                         float* __restrict__ xm, float* __restrict__ z, int blk){
    // grid (L/TT, 2, 4), block 256 (e within half)
    int s = blockIdx.z; int j = (s>>1)*3 + blk;
    int l0 = blockIdx.x*TT;
    int e = blockIdx.y*256 + threadIdx.x;
    __shared__ float xs[TT][D];
    int tb0 = s*L + l0;
    for (int i = threadIdx.x; i < TT*D; i += 256){
        int t = i >> 7, dd = i & 127;
        xs[t][dd] = hn[(tb0+t)*D + dd];
    }
    __syncthreads();
    const float* wr = W + (j*2*DI + e)*D;
    float acc[TT];
    #pragma unroll
    for (int t=0;t<TT;++t) acc[t]=0.f;
    for (int dd=0; dd<D; ++dd){
        float wv = wr[dd];
        #pragma unroll
        for (int t=0;t<TT;++t) acc[t] += xs[t][dd]*wv;
    }
    if (e < DI){
        #pragma unroll
        for (int t=0;t<TT;++t) xm[(tb0+t)*DI + e] = acc[t];
    } else {
        int e2 = e - DI;
        #pragma unroll
        for (int t=0;t<TT;++t) z[(tb0+t)*DI + e2] = acc[t];
    }
}

// ---------------- causal depthwise conv width 4 + bias + silu
__global__ void k_conv(const float* __restrict__ xm, const float* __restrict__ cw,
                       const float* __restrict__ cb, float* __restrict__ xc, int blk){
    // grid (L, 4), block 256
    int s = blockIdx.y; int j = (s>>1)*3 + blk;
    int l = blockIdx.x; int e = threadIdx.x;
    int sb = s*L;
    const float* w = cw + (j*DI + e)*4;
    float acc = cb[j*DI + e];
    #pragma unroll
    for (int k=0;k<4;++k){
        int ll = l + k - 3;
        if (ll >= 0) acc += xm[(sb+ll)*DI + e]*w[k];
    }
    xc[(sb+l)*DI + e] = siluf_(acc);
}

// ---------------- x_proj: dbc = xc @ W^T (40 outputs), split dt_raw / Bc / Cc
__global__ void k_xproj(const float* __restrict__ xc, const float* __restrict__ W,
                        float* __restrict__ dtr, float* __restrict__ Bc,
                        float* __restrict__ Cc, int blk){
    // grid (L/4, 4), block 256 = 4 tokens x 64 lanes
    int s = blockIdx.y; int j = (s>>1)*3 + blk;
    int t = threadIdx.x >> 6;
    int lane = threadIdx.x & 63;
    int l = blockIdx.x*4 + t;
    int tb = s*L + l;
    __shared__ float xs[4][DI];
    for (int i = lane; i < DI; i += 64) xs[t][i] = xc[tb*DI + i];
    __syncthreads();
    if (lane < 40){
        const float* wr = W + (j*40 + lane)*DI;
        float acc = 0.f;
        #pragma unroll 8
        for (int e=0;e<DI;++e) acc += xs[t][e]*wr[e];
        if (lane < 8)       dtr[tb*RK + lane] = acc;
        else if (lane < 24) Bc[tb*NS + (lane-8)] = acc;
        else                Cc[tb*NS + (lane-24)] = acc;
    }
}

// ---------------- dt_proj + softplus
__global__ void k_dtproj(const float* __restrict__ dtr, const float* __restrict__ Wdt,
                         const float* __restrict__ bdt, float* __restrict__ dt, int blk){
    // grid (L/TT, 4), block 256 (e)
    int s = blockIdx.y; int j = (s>>1)*3 + blk;
    int l0 = blockIdx.x*TT;
    int e = threadIdx.x;
    __shared__ float rs[TT][RK];
    int tb0 = s*L + l0;
    for (int i = threadIdx.x; i < TT*RK; i += 256)
        rs[i>>3][i&7] = dtr[(tb0 + (i>>3))*RK + (i&7)];
    __syncthreads();
    const float* wr = Wdt + (j*DI + e)*RK;
    float wv[RK];
    #pragma unroll
    for (int r=0;r<RK;++r) wv[r] = wr[r];
    float bb = bdt[j*DI + e];
    for (int t=0;t<TT;++t){
        float acc = bb;
        #pragma unroll
        for (int r=0;r<RK;++r) acc += rs[t][r]*wv[r];
        dt[(tb0+t)*DI + e] = (acc > 20.f) ? acc : log1pf(__expf(acc));
    }
}

// ---------------- chunked scan phase 1: per-chunk affine summary (Aprod, Bend)
// h_out = Aprod * h_in + Bend over the chunk; thread = (d-group lane, n)
__global__ void k_scan1(const float* __restrict__ dt, const float* __restrict__ xcv,
                        const float* __restrict__ Bc, const float* __restrict__ A_log,
                        float* __restrict__ Aprod, float* __restrict__ Bend, int blk){
    // grid (16, NC, 4), block 256
    int s = blockIdx.z; int j = (s>>1)*3 + blk;
    int c = blockIdx.y;
    int tid = threadIdx.x;
    int dl = tid >> 4, n = tid & 15;
    int d = blockIdx.x*16 + dl;
    float A = -__expf(A_log[(j*DI + d)*NS + n]);
    float aprod = 1.f, hloc = 0.f;
    int sb = s*L + c*CHUNK;
    #pragma unroll 4
    for (int i=0;i<CHUNK;++i){
        int tb = sb + i;
        float dtv = dt[tb*DI + d];
        float xv  = xcv[tb*DI + d];
        float bv  = Bc[tb*NS + n];
        float dA  = __expf(dtv*A);
        aprod *= dA;
        hloc = dA*hloc + dtv*bv*xv;
    }
    int idx = ((s*NC + c)*16 + blockIdx.x)*256 + tid;
    Aprod[idx] = aprod;
    Bend[idx]  = hloc;
}

// ---------------- chunked scan phase 2: fold preceding summaries, rescan chunk, emit y
__global__ void k_scan2(const float* __restrict__ dt, const float* __restrict__ xcv,
                        const float* __restrict__ Bc, const float* __restrict__ Cc,
                        const float* __restrict__ A_log,
                        const float* __restrict__ Aprod, const float* __restrict__ Bend,
                        float* __restrict__ y, int blk){
    // grid (16, NC, 4), block 256
    int s = blockIdx.z; int j = (s>>1)*3 + blk;
    int c = blockIdx.y;
    int tid = threadIdx.x;
    int dl = tid >> 4, n = tid & 15;
    int d = blockIdx.x*16 + dl;
    float A = -__expf(A_log[(j*DI + d)*NS + n]);
    // prefix over chunks 0..c-1 (independent coalesced loads, short fma chain)
    float h = 0.f;
    for (int k=0;k<c;++k){
        int idx = ((s*NC + k)*16 + blockIdx.x)*256 + tid;
        h = Aprod[idx]*h + Bend[idx];
    }
    int sb = s*L + c*CHUNK;
    #pragma unroll 4
    for (int i=0;i<CHUNK;++i){
        int tb = sb + i;
        float dtv = dt[tb*DI + d];
        float xv  = xcv[tb*DI + d];
        float bv  = Bc[tb*NS + n];
        float cv  = Cc[tb*NS + n];
        float dA  = __expf(dtv*A);
        h = dA*h + dtv*bv*xv;
        float p = h*cv;
        p += __shfl_xor(p, 1, 16);
        p += __shfl_xor(p, 2, 16);
        p += __shfl_xor(p, 4, 16);
        p += __shfl_xor(p, 8, 16);
        if (n == 0) y[tb*DI + d] = p;
    }
}

// ---------------- fused gate + out_proj
__global__ void k_outproj(const float* __restrict__ y, const float* __restrict__ xcv,
                          const float* __restrict__ z, const float* __restrict__ Dp,
                          const float* __restrict__ W, float* __restrict__ cur, int blk){
    // grid (L/TT, 4), block 128 (dout)
    int s = blockIdx.y; int j = (s>>1)*3 + blk;
    int l0 = blockIdx.x*TT;
    int dout = threadIdx.x;
    __shared__ float ys[TT][DI];
    int tb0 = s*L + l0;
    const float* Dpj = Dp + j*DI;
    for (int i = threadIdx.x; i < TT*DI; i += 128){
        int t = i >> 8, e = i & 255;
        int a = (tb0+t)*DI + e;
        ys[t][e] = (y[a] + Dpj[e]*xcv[a]) * siluf_(z[a]);
    }
    __syncthreads();
    const float* wr = W + (j*D + dout)*DI;
    float acc[TT];
    #pragma unroll
    for (int t=0;t<TT;++t) acc[t]=0.f;
    for (int e=0;e<DI;++e){
        float wv = wr[e];
        #pragma unroll
        for (int t=0;t<TT;++t) acc[t] += ys[t][e]*wv;
    }
    #pragma unroll
    for (int t=0;t<TT;++t) cur[(tb0+t)*D + dout] = acc[t];
}

// ---------------- final combine: out0 (B,D,L), rf (B,L,D), rb (B,L,D reversed-domain)
__global__ void k_final(const float* __restrict__ cur, const float* __restrict__ res,
                        float* __restrict__ out){
    // grid (L, B), block 128
    int l = blockIdx.x, b = blockIdx.y, d = threadIdx.x;
    int tf = (b*L + l)*D + d;
    int tbk = ((2+b)*L + (L-1-l))*D + d;   // bwd at reversed index
    float f  = cur[tf] + res[tf];
    float bw = cur[tbk] + res[tbk];
    out[(b*D + d)*L + l] = f + bw;                               // out0 (2,128,2048)
    out[2*D*L + (b*L + l)*D + d] = res[tf];                      // rf
    out[2*D*L + 2*L*D + ((2+b)*L + l)*D - 2*L*D + d] = res[((2+b)*L + l)*D + d]; // rb
}

extern "C" void kernel_launch(void* const* d_in, const int* in_sizes, int n_in,
                              void* d_out, int out_size, void* d_ws, size_t ws_size,
                              hipStream_t stream){
    const float* x         = (const float*)d_in[0];
    const float* convd_w   = (const float*)d_in[1];
    const float* convd_b   = (const float*)d_in[2];
    const float* ln_w      = (const float*)d_in[3];
    const float* ln_b      = (const float*)d_in[4];
    const float* in_proj_w = (const float*)d_in[5];
    const float* conv_w    = (const float*)d_in[6];
    const float* conv_b    = (const float*)d_in[7];
    const float* xproj_w   = (const float*)d_in[8];
    const float* dtproj_w  = (const float*)d_in[9];
    const float* dtproj_b  = (const float*)d_in[10];
    const float* A_log     = (const float*)d_in[11];
    const float* Dparam    = (const float*)d_in[12];
    const float* outproj_w = (const float*)d_in[13];

    float* ws = (float*)d_ws;
    const size_t SZ_D  = (size_t)NSTREAM*L*D;    // 1,048,576
    const size_t SZ_DI = (size_t)NSTREAM*L*DI;   // 2,097,152
    float* h   = ws;            ws += SZ_D;
    float* res = ws;            ws += SZ_D;
    float* cur = ws;            ws += SZ_D;
    float* hn  = ws;            ws += SZ_D;
    float* xm  = ws;            ws += SZ_DI;
    float* z   = ws;            ws += SZ_DI;
    float* xc  = ws;            ws += SZ_DI;
    float* dt  = ws;            ws += SZ_DI;
    float* y   = ws;            ws += SZ_DI;
    float* dtr = ws;            ws += (size_t)NSTREAM*L*RK;
    float* Bc  = ws;            ws += (size_t)NSTREAM*L*NS;
    float* Cc  = ws;            ws += (size_t)NSTREAM*L*NS;
    // scan chunk summaries alias xm (dead after k_conv within each layer):
    // each is NSTREAM*NC*DI*NS = 524288 floats; xm holds 2,097,152 — fits.
    float* Aprod = xm;
    float* Bend  = xm + (size_t)NSTREAM*NC*DI*NS;

    k_downsample<<<dim3(L,B), 128, 0, stream>>>(x, convd_w, convd_b, h);

    for (int blk = 0; blk < 3; ++blk){
        k_resln<<<dim3(L,NSTREAM), 128, 0, stream>>>(blk==0 ? h : cur, res, ln_w, ln_b, hn, blk, blk==0);
        k_inproj<<<dim3(L/TT,2,NSTREAM), 256, 0, stream>>>(hn, in_proj_w, xm, z, blk);
        k_conv<<<dim3(L,NSTREAM), 256, 0, stream>>>(xm, conv_w, conv_b, xc, blk);
        k_xproj<<<dim3(L/4,NSTREAM), 256, 0, stream>>>(xc, xproj_w, dtr, Bc, Cc, blk);
        k_dtproj<<<dim3(L/TT,NSTREAM), 256, 0, stream>>>(dtr, dtproj_w, dtproj_b, dt, blk);
        k_scan1<<<dim3(16,NC,NSTREAM), 256, 0, stream>>>(dt, xc, Bc, A_log, Aprod, Bend, blk);
        k_scan2<<<dim3(16,NC,NSTREAM), 256, 0, stream>>>(dt, xc, Bc, Cc, A_log, Aprod, Bend, y, blk);
        k_outproj<<<dim3(L/TT,NSTREAM), 128, 0, stream>>>(y, xc, z, Dparam, outproj_w, cur, blk);
    }

    k_final<<<dim3(L,B), 128, 0, stream>>>(cur, res, (float*)d_out);
}

// Round 3
// 451.176 us; speedup vs baseline: 6.7741x; 1.6011x over previous
//
#include <hip/hip_runtime.h>
#include <hip/hip_bf16.h>
#include <math.h>

// Problem constants
#define B    2
#define CIN  64
#define LIN  8192
#define L    2048
#define D    128
#define DI   256
#define NS   16
#define RK   8
#define NSTREAM 4       // (dir, batch): s = dir*2 + b
#define TT   8
#define CHUNK 64
#define NC   (L/CHUNK)  // 32
#define TOK  (NSTREAM*L) // 8192 token-rows (4096 fwd, 4096 bwd)

typedef short  bfrag __attribute__((ext_vector_type(8)));  // 8 bf16 (4 VGPRs)
typedef float  facc  __attribute__((ext_vector_type(4)));  // 4 fp32 acc

__device__ __forceinline__ float sigmoidf_(float x){ return 1.f/(1.f+__expf(-x)); }
__device__ __forceinline__ float siluf_(float x){ return x*sigmoidf_(x); }
__device__ __forceinline__ ushort f2bf(float f){
    unsigned u = __float_as_uint(f);
    u += 0x7fffu + ((u>>16)&1u);       // round-to-nearest-even
    return (ushort)(u>>16);
}

// ---------------- fp32 -> bf16 weight conversion
__global__ void k_cvt(const float* __restrict__ src, ushort* __restrict__ dst, int n){
    int i = blockIdx.x*256 + threadIdx.x;
    if (i < n) dst[i] = f2bf(src[i]);
}
// xproj (6,40,256) -> padded (6,64,256), rows >=40 zeroed
__global__ void k_cvt_xw(const float* __restrict__ src, ushort* __restrict__ dst){
    int i = blockIdx.x*256 + threadIdx.x;   // 6*64*256 = 98304
    int k = i & 255, nr = (i>>8) & 63, j = i>>14;
    dst[i] = (nr < 40) ? f2bf(src[((size_t)j*40 + nr)*256 + k]) : (ushort)0;
}

// ---------------- pack downsample patches: x (B,CIN,LIN) -> xp (B*L, CIN*4) bf16
__global__ void k_patch(const float* __restrict__ x, ushort* __restrict__ xp){
    // grid (L/256, CIN, B), block 256; thread -> one output token l for channel c
    int l = blockIdx.x*256 + threadIdx.x;
    int c = blockIdx.y, b = blockIdx.z;
    float4 v = *(const float4*)(x + ((size_t)(b*CIN + c))*LIN + 4*l);
    ushort4 o; o.x=f2bf(v.x); o.y=f2bf(v.y); o.z=f2bf(v.z); o.w=f2bf(v.w);
    *(ushort4*)(xp + ((size_t)(b*L + l))*(CIN*4) + c*4) = o;
}

// ---------------- MFMA core: 32x32 wave tile of C = X(M,K) @ W(N,K)^T
template<int K>
__device__ __forceinline__ void mm_core(const ushort* __restrict__ X,
                                        const ushort* __restrict__ Wt,
                                        facc (&acc)[2][2]){
    const int lane = threadIdx.x & 63;
    const int q = lane >> 4, r = lane & 15;
    const bfrag* xa0 = (const bfrag*)(X  + (size_t)r*K      + q*8);
    const bfrag* xa1 = (const bfrag*)(X  + (size_t)(r+16)*K + q*8);
    const bfrag* wb0 = (const bfrag*)(Wt + (size_t)r*K      + q*8);
    const bfrag* wb1 = (const bfrag*)(Wt + (size_t)(r+16)*K + q*8);
    #pragma unroll
    for (int kb = 0; kb < K/32; ++kb){
        bfrag a0 = xa0[kb*4], a1 = xa1[kb*4];   // 32 elems = 4 bfrag stride
        bfrag b0 = wb0[kb*4], b1 = wb1[kb*4];
        acc[0][0] = __builtin_amdgcn_mfma_f32_16x16x32_bf16(a0,b0,acc[0][0],0,0,0);
        acc[0][1] = __builtin_amdgcn_mfma_f32_16x16x32_bf16(a0,b1,acc[0][1],0,0,0);
        acc[1][0] = __builtin_amdgcn_mfma_f32_16x16x32_bf16(a1,b0,acc[1][0],0,0,0);
        acc[1][1] = __builtin_amdgcn_mfma_f32_16x16x32_bf16(a1,b1,acc[1][1],0,0,0);
    }
}
// C/D layout: col = lane&15, row = (lane>>4)*4 + reg  (m89-verified)

// ---------------- downsample GEMM: xp(4096,256) @ wbd(128,256)^T + bias, silu, dual write
__global__ void k_gemm_down(const ushort* __restrict__ xp, const ushort* __restrict__ wd,
                            const float* __restrict__ bias, float* __restrict__ h){
    // grid (64, 2), block 256
    int w = threadIdx.x>>6, lane = threadIdx.x&63, rw = w>>1, cw = w&1;
    int m0 = blockIdx.x*64 + rw*32;
    int n0 = blockIdx.y*64 + cw*32;
    facc acc[2][2] = {};
    mm_core<256>(xp + (size_t)m0*256, wd + (size_t)n0*256, acc);
    int q = lane>>4, rr = lane&15;
    #pragma unroll
    for (int im=0; im<2; ++im)
    #pragma unroll
    for (int in=0; in<2; ++in){
        int col = n0 + in*16 + rr;
        float bv = bias[col];
        #pragma unroll
        for (int r2=0; r2<4; ++r2){
            int row = m0 + im*16 + q*4 + r2;
            int b = row >> 11, l = row & 2047;
            float v = siluf_(acc[im][in][r2] + bv);
            h[((size_t)(b*L + l))*D + col] = v;
            h[((size_t)((2+b)*L + (L-1-l)))*D + col] = v;
        }
    }
}

// ---------------- residual + layernorm -> bf16 hn
__global__ void k_resln(const float* __restrict__ curIn, float* __restrict__ res,
                        const float* __restrict__ lnw, const float* __restrict__ lnb,
                        ushort* __restrict__ hnb, int blk, int first){
    int l = blockIdx.x, s = blockIdx.y, d = threadIdx.x;
    int j = (s>>1)*3 + blk;
    int tb = s*L + l;
    float r = curIn[tb*D + d];
    if (!first) r += res[tb*D + d];
    res[tb*D + d] = r;
    __shared__ float red[128];
    red[d] = r; __syncthreads();
    for (int off=64; off; off>>=1){ if (d<off) red[d]+=red[d+off]; __syncthreads(); }
    float mean = red[0]*(1.f/128.f);
    __syncthreads();
    float c = r - mean;
    red[d] = c*c; __syncthreads();
    for (int off=64; off; off>>=1){ if (d<off) red[d]+=red[d+off]; __syncthreads(); }
    float var = red[0]*(1.f/128.f);
    float rstd = rsqrtf(var + 1e-5f);
    hnb[(size_t)tb*D + d] = f2bf(c*rstd*lnw[j*D + d] + lnb[j*D + d]);
}

// ---------------- in_proj GEMM: hnb(8192,128) @ wbi[j](512,128)^T -> xm | z (fp32)
__global__ void k_gemm_in(const ushort* __restrict__ hnb, const ushort* __restrict__ wbi,
                          float* __restrict__ xm, float* __restrict__ z, int blk){
    // grid (128, 8), block 256
    int w = threadIdx.x>>6, lane = threadIdx.x&63, rw = w>>1, cw = w&1;
    int m0 = blockIdx.x*64 + rw*32;
    int n0 = blockIdx.y*64 + cw*32;
    int dir = blockIdx.x >> 6;            // rows 0..4095 fwd, 4096..8191 bwd
    int j = dir*3 + blk;
    facc acc[2][2] = {};
    mm_core<128>(hnb + (size_t)m0*128, wbi + ((size_t)j*512 + n0)*128, acc);
    int q = lane>>4, rr = lane&15;
    #pragma unroll
    for (int im=0; im<2; ++im)
    #pragma unroll
    for (int in=0; in<2; ++in){
        int e = n0 + in*16 + rr;
        #pragma unroll
        for (int r2=0; r2<4; ++r2){
            int row = m0 + im*16 + q*4 + r2;
            float v = acc[im][in][r2];
            if (e < DI) xm[(size_t)row*DI + e] = v;
            else        z [(size_t)row*DI + (e-DI)] = v;
        }
    }
}

// ---------------- causal depthwise conv + silu -> xc fp32 + bf16
__global__ void k_conv(const float* __restrict__ xm, const float* __restrict__ cw,
                       const float* __restrict__ cb, float* __restrict__ xc,
                       ushort* __restrict__ xcb, int blk){
    int s = blockIdx.y; int j = (s>>1)*3 + blk;
    int l = blockIdx.x; int e = threadIdx.x;
    int sb = s*L;
    const float* w = cw + ((size_t)j*DI + e)*4;
    float acc = cb[j*DI + e];
    #pragma unroll
    for (int k=0;k<4;++k){
        int ll = l + k - 3;
        if (ll >= 0) acc += xm[(size_t)(sb+ll)*DI + e]*w[k];
    }
    float v = siluf_(acc);
    xc [(size_t)(sb+l)*DI + e] = v;
    xcb[(size_t)(sb+l)*DI + e] = f2bf(v);
}

// ---------------- x_proj GEMM: xcb(8192,256) @ wbx[j](64pad,256)^T -> dtr/Bc/Cc
__global__ void k_gemm_x(const ushort* __restrict__ xcb, const ushort* __restrict__ wbx,
                         float* __restrict__ dtr, float* __restrict__ Bc,
                         float* __restrict__ Cc, int blk){
    // grid (128, 1), block 256
    int w = threadIdx.x>>6, lane = threadIdx.x&63, rw = w>>1, cw = w&1;
    int m0 = blockIdx.x*64 + rw*32;
    int n0 = cw*32;
    int dir = blockIdx.x >> 6;
    int j = dir*3 + blk;
    facc acc[2][2] = {};
    mm_core<256>(xcb + (size_t)m0*256, wbx + ((size_t)j*64 + n0)*256, acc);
    int q = lane>>4, rr = lane&15;
    #pragma unroll
    for (int im=0; im<2; ++im)
    #pragma unroll
    for (int in=0; in<2; ++in){
        int col = n0 + in*16 + rr;
        #pragma unroll
        for (int r2=0; r2<4; ++r2){
            int row = m0 + im*16 + q*4 + r2;
            float v = acc[im][in][r2];
            if      (col < 8)  dtr[(size_t)row*RK + col] = v;
            else if (col < 24) Bc [(size_t)row*NS + (col-8)] = v;
            else if (col < 40) Cc [(size_t)row*NS + (col-24)] = v;
        }
    }
}

// ---------------- dt_proj + softplus (fp32, K=8)
__global__ void k_dtproj(const float* __restrict__ dtr, const float* __restrict__ Wdt,
                         const float* __restrict__ bdt, float* __restrict__ dt, int blk){
    int s = blockIdx.y; int j = (s>>1)*3 + blk;
    int l0 = blockIdx.x*TT;
    int e = threadIdx.x;
    __shared__ float rs[TT][RK];
    int tb0 = s*L + l0;
    for (int i = threadIdx.x; i < TT*RK; i += 256)
        rs[i>>3][i&7] = dtr[(size_t)(tb0 + (i>>3))*RK + (i&7)];
    __syncthreads();
    const float* wr = Wdt + ((size_t)j*DI + e)*RK;
    float wv[RK];
    #pragma unroll
    for (int r=0;r<RK;++r) wv[r] = wr[r];
    float bb = bdt[j*DI + e];
    for (int t=0;t<TT;++t){
        float acc = bb;
        #pragma unroll
        for (int r=0;r<RK;++r) acc += rs[t][r]*wv[r];
        dt[(size_t)(tb0+t)*DI + e] = (acc > 20.f) ? acc : log1pf(__expf(acc));
    }
}

// ---------------- chunked scan phase 1
__global__ void k_scan1(const float* __restrict__ dt, const float* __restrict__ xcv,
                        const float* __restrict__ Bc, const float* __restrict__ A_log,
                        float* __restrict__ Aprod, float* __restrict__ Bend, int blk){
    int s = blockIdx.z; int j = (s>>1)*3 + blk;
    int c = blockIdx.y;
    int tid = threadIdx.x;
    int dl = tid >> 4, n = tid & 15;
    int d = blockIdx.x*16 + dl;
    float A = -__expf(A_log[((size_t)j*DI + d)*NS + n]);
    float aprod = 1.f, hloc = 0.f;
    int sb = s*L + c*CHUNK;
    #pragma unroll 4
    for (int i=0;i<CHUNK;++i){
        int tb = sb + i;
        float dtv = dt[(size_t)tb*DI + d];
        float xv  = xcv[(size_t)tb*DI + d];
        float bv  = Bc[(size_t)tb*NS + n];
        float dA  = __expf(dtv*A);
        aprod *= dA;
        hloc = dA*hloc + dtv*bv*xv;
    }
    int idx = ((s*NC + c)*16 + blockIdx.x)*256 + tid;
    Aprod[idx] = aprod;
    Bend[idx]  = hloc;
}

// ---------------- chunked scan phase 2
__global__ void k_scan2(const float* __restrict__ dt, const float* __restrict__ xcv,
                        const float* __restrict__ Bc, const float* __restrict__ Cc,
                        const float* __restrict__ A_log,
                        const float* __restrict__ Aprod, const float* __restrict__ Bend,
                        float* __restrict__ y, int blk){
    int s = blockIdx.z; int j = (s>>1)*3 + blk;
    int c = blockIdx.y;
    int tid = threadIdx.x;
    int dl = tid >> 4, n = tid & 15;
    int d = blockIdx.x*16 + dl;
    float A = -__expf(A_log[((size_t)j*DI + d)*NS + n]);
    float h = 0.f;
    for (int k=0;k<c;++k){
        int idx = ((s*NC + k)*16 + blockIdx.x)*256 + tid;
        h = Aprod[idx]*h + Bend[idx];
    }
    int sb = s*L + c*CHUNK;
    #pragma unroll 4
    for (int i=0;i<CHUNK;++i){
        int tb = sb + i;
        float dtv = dt[(size_t)tb*DI + d];
        float xv  = xcv[(size_t)tb*DI + d];
        float bv  = Bc[(size_t)tb*NS + n];
        float cv  = Cc[(size_t)tb*NS + n];
        float dA  = __expf(dtv*A);
        h = dA*h + dtv*bv*xv;
        float p = h*cv;
        p += __shfl_xor(p, 1, 16);
        p += __shfl_xor(p, 2, 16);
        p += __shfl_xor(p, 4, 16);
        p += __shfl_xor(p, 8, 16);
        if (n == 0) y[(size_t)tb*DI + d] = p;
    }
}

// ---------------- gate: g = (y + D*xc)*silu(z) -> bf16
__global__ void k_gate(const float* __restrict__ y, const float* __restrict__ xc,
                       const float* __restrict__ z, const float* __restrict__ Dp,
                       ushort* __restrict__ g, int blk){
    int idx = blockIdx.x*256 + threadIdx.x;   // each handles 4 elems
    int base = idx*4;
    int tb = base >> 8;
    int e  = base & 255;
    int s  = tb >> 11;
    int j  = (s>>1)*3 + blk;
    float4 yv = *(const float4*)(y + base);
    float4 xv = *(const float4*)(xc + base);
    float4 zv = *(const float4*)(z + base);
    float4 dv = *(const float4*)(Dp + (size_t)j*DI + e);
    ushort4 o;
    o.x = f2bf((yv.x + dv.x*xv.x)*siluf_(zv.x));
    o.y = f2bf((yv.y + dv.y*xv.y)*siluf_(zv.y));
    o.z = f2bf((yv.z + dv.z*xv.z)*siluf_(zv.z));
    o.w = f2bf((yv.w + dv.w*xv.w)*siluf_(zv.w));
    *(ushort4*)(g + base) = o;
}

// ---------------- out_proj GEMM: g(8192,256) @ wbo[j](128,256)^T -> cur fp32
__global__ void k_gemm_out(const ushort* __restrict__ g, const ushort* __restrict__ wbo,
                           float* __restrict__ cur, int blk){
    // grid (128, 2), block 256
    int w = threadIdx.x>>6, lane = threadIdx.x&63, rw = w>>1, cw = w&1;
    int m0 = blockIdx.x*64 + rw*32;
    int n0 = blockIdx.y*64 + cw*32;
    int dir = blockIdx.x >> 6;
    int j = dir*3 + blk;
    facc acc[2][2] = {};
    mm_core<256>(g + (size_t)m0*256, wbo + ((size_t)j*128 + n0)*256, acc);
    int q = lane>>4, rr = lane&15;
    #pragma unroll
    for (int im=0; im<2; ++im)
    #pragma unroll
    for (int in=0; in<2; ++in){
        int col = n0 + in*16 + rr;
        #pragma unroll
        for (int r2=0; r2<4; ++r2){
            int row = m0 + im*16 + q*4 + r2;
            cur[(size_t)row*D + col] = acc[im][in][r2];
        }
    }
}

// ---------------- final combine
__global__ void k_final(const float* __restrict__ cur, const float* __restrict__ res,
                        float* __restrict__ out){
    int l = blockIdx.x, b = blockIdx.y, d = threadIdx.x;
    int tf = (b*L + l)*D + d;
    int tbk = ((2+b)*L + (L-1-l))*D + d;
    float f  = cur[tf] + res[tf];
    float bw = cur[tbk] + res[tbk];
    out[((size_t)(b*D + d))*L + l] = f + bw;
    out[(size_t)2*D*L + (size_t)(b*L + l)*D + d] = res[tf];
    out[(size_t)2*D*L + (size_t)((2+b)*L + l)*D + d] = res[((2+b)*L + l)*D + d];
}

extern "C" void kernel_launch(void* const* d_in, const int* in_sizes, int n_in,
                              void* d_out, int out_size, void* d_ws, size_t ws_size,
                              hipStream_t stream){
    const float* x         = (const float*)d_in[0];
    const float* convd_w   = (const float*)d_in[1];
    const float* convd_b   = (const float*)d_in[2];
    const float* ln_w      = (const float*)d_in[3];
    const float* ln_b      = (const float*)d_in[4];
    const float* in_proj_w = (const float*)d_in[5];
    const float* conv_w    = (const float*)d_in[6];
    const float* conv_b    = (const float*)d_in[7];
    const float* xproj_w   = (const float*)d_in[8];
    const float* dtproj_w  = (const float*)d_in[9];
    const float* dtproj_b  = (const float*)d_in[10];
    const float* A_log     = (const float*)d_in[11];
    const float* Dparam    = (const float*)d_in[12];
    const float* outproj_w = (const float*)d_in[13];

    float* ws = (float*)d_ws;
    const size_t SZ_D  = (size_t)TOK*D;    // 1,048,576 floats
    const size_t SZ_DI = (size_t)TOK*DI;   // 2,097,152 floats
    float* h     = ws; ws += SZ_D;
    float* res   = ws; ws += SZ_D;
    float* cur   = ws; ws += SZ_D;
    float* hnreg = ws; ws += SZ_D;   // hosts hnb (2MB) + xp (2MB)
    float* xm    = ws; ws += SZ_DI;  // also hosts Aprod/Bend after conv
    float* z     = ws; ws += SZ_DI;
    float* xc    = ws; ws += SZ_DI;
    float* dt    = ws; ws += SZ_DI;  // first 4MB re-used as g (bf16) after scan2
    float* y     = ws; ws += SZ_DI;  // first 4MB re-used as xcb (bf16) until scan2
    float* dtr   = ws; ws += (size_t)TOK*RK;
    float* Bc    = ws; ws += (size_t)TOK*NS;
    float* Cc    = ws; ws += (size_t)TOK*NS;
    ushort* wbd  = (ushort*)ws;                 // (128,256)       32768
    ushort* wbi  = wbd + 32768;                 // (6,512,128)    393216
    ushort* wbx  = wbi + 393216;                // (6,64,256) pad  98304
    ushort* wbo  = wbx + 98304;                 // (6,128,256)    196608

    ushort* hnb  = (ushort*)hnreg;                 // TOK*D ushorts
    ushort* xp   = hnb + (size_t)TOK*D;            // 4096*256 ushorts
    ushort* xcb  = (ushort*)y;                     // TOK*DI ushorts (dead before scan2 writes y)
    ushort* g    = (ushort*)dt;                    // TOK*DI ushorts (written after scan2)
    float* Aprod = xm;
    float* Bend  = xm + (size_t)NSTREAM*NC*DI*NS;  // 524288 floats each

    // weight conversions (cheap, every launch — graph-safe)
    k_cvt<<<128, 256, 0, stream>>>(convd_w, wbd, 32768);
    k_cvt<<<1536, 256, 0, stream>>>(in_proj_w, wbi, 393216);
    k_cvt<<<768, 256, 0, stream>>>(outproj_w, wbo, 196608);
    k_cvt_xw<<<384, 256, 0, stream>>>(xproj_w, wbx);

    k_patch<<<dim3(L/256, CIN, B), 256, 0, stream>>>(x, xp);
    k_gemm_down<<<dim3(64, 2), 256, 0, stream>>>(xp, wbd, convd_b, h);

    for (int blk = 0; blk < 3; ++blk){
        k_resln<<<dim3(L, NSTREAM), 128, 0, stream>>>(blk==0 ? h : cur, res, ln_w, ln_b, hnb, blk, blk==0);
        k_gemm_in<<<dim3(128, 8), 256, 0, stream>>>(hnb, wbi, xm, z, blk);
        k_conv<<<dim3(L, NSTREAM), 256, 0, stream>>>(xm, conv_w, conv_b, xc, xcb, blk);
        k_gemm_x<<<dim3(128, 1), 256, 0, stream>>>(xcb, wbx, dtr, Bc, Cc, blk);
        k_dtproj<<<dim3(L/TT, NSTREAM), 256, 0, stream>>>(dtr, dtproj_w, dtproj_b, dt, blk);
        k_scan1<<<dim3(16, NC, NSTREAM), 256, 0, stream>>>(dt, xc, Bc, A_log, Aprod, Bend, blk);
        k_scan2<<<dim3(16, NC, NSTREAM), 256, 0, stream>>>(dt, xc, Bc, Cc, A_log, Aprod, Bend, y, blk);
        k_gate<<<2048, 256, 0, stream>>>(y, xc, z, Dparam, g, blk);
        k_gemm_out<<<dim3(128, 2), 256, 0, stream>>>(g, wbo, cur, blk);
    }

    k_final<<<dim3(L, B), 128, 0, stream>>>(cur, res, (float*)d_out);
}

// Round 4
// 400.985 us; speedup vs baseline: 7.6221x; 1.1252x over previous
//
#include <hip/hip_runtime.h>
#include <hip/hip_bf16.h>
#include <math.h>

// Problem constants
#define B    2
#define CIN  64
#define LIN  8192
#define L    2048
#define D    128
#define DI   256
#define NS   16
#define RK   8
#define NSTREAM 4       // (dir, batch): s = dir*2 + b
#define TT   8
#define CHUNK 16
#define NC   (L/CHUNK)  // 128
#define TOK  (NSTREAM*L) // 8192 token-rows

typedef short  bfrag __attribute__((ext_vector_type(8)));  // 8 bf16 (4 VGPRs)
typedef float  facc  __attribute__((ext_vector_type(4)));  // 4 fp32 acc

__device__ __forceinline__ float sigmoidf_(float x){ return 1.f/(1.f+__expf(-x)); }
__device__ __forceinline__ float siluf_(float x){ return x*sigmoidf_(x); }
__device__ __forceinline__ ushort f2bf(float f){
    unsigned u = __float_as_uint(f);
    u += 0x7fffu + ((u>>16)&1u);       // round-to-nearest-even
    return (ushort)(u>>16);
}

// ---------------- fp32 -> bf16 weight conversion
__global__ void k_cvt(const float* __restrict__ src, ushort* __restrict__ dst, int n){
    int i = blockIdx.x*256 + threadIdx.x;
    if (i < n) dst[i] = f2bf(src[i]);
}
// xproj (6,40,256) -> padded (6,64,256), rows >=40 zeroed
__global__ void k_cvt_xw(const float* __restrict__ src, ushort* __restrict__ dst){
    int i = blockIdx.x*256 + threadIdx.x;   // 6*64*256 = 98304
    int k = i & 255, nr = (i>>8) & 63, j = i>>14;
    dst[i] = (nr < 40) ? f2bf(src[((size_t)j*40 + nr)*256 + k]) : (ushort)0;
}

// ---------------- pack downsample patches: x (B,CIN,LIN) -> xp (B*L, CIN*4) bf16
__global__ void k_patch(const float* __restrict__ x, ushort* __restrict__ xp){
    int l = blockIdx.x*256 + threadIdx.x;
    int c = blockIdx.y, b = blockIdx.z;
    float4 v = *(const float4*)(x + ((size_t)(b*CIN + c))*LIN + 4*l);
    ushort4 o; o.x=f2bf(v.x); o.y=f2bf(v.y); o.z=f2bf(v.z); o.w=f2bf(v.w);
    *(ushort4*)(xp + ((size_t)(b*L + l))*(CIN*4) + c*4) = o;
}

// ---------------- MFMA core: 32x32 wave tile of C = X(M,K) @ W(N,K)^T
template<int K>
__device__ __forceinline__ void mm_core(const ushort* __restrict__ X,
                                        const ushort* __restrict__ Wt,
                                        facc (&acc)[2][2]){
    const int lane = threadIdx.x & 63;
    const int q = lane >> 4, r = lane & 15;
    const bfrag* xa0 = (const bfrag*)(X  + (size_t)r*K      + q*8);
    const bfrag* xa1 = (const bfrag*)(X  + (size_t)(r+16)*K + q*8);
    const bfrag* wb0 = (const bfrag*)(Wt + (size_t)r*K      + q*8);
    const bfrag* wb1 = (const bfrag*)(Wt + (size_t)(r+16)*K + q*8);
    #pragma unroll
    for (int kb = 0; kb < K/32; ++kb){
        bfrag a0 = xa0[kb*4], a1 = xa1[kb*4];
        bfrag b0 = wb0[kb*4], b1 = wb1[kb*4];
        acc[0][0] = __builtin_amdgcn_mfma_f32_16x16x32_bf16(a0,b0,acc[0][0],0,0,0);
        acc[0][1] = __builtin_amdgcn_mfma_f32_16x16x32_bf16(a0,b1,acc[0][1],0,0,0);
        acc[1][0] = __builtin_amdgcn_mfma_f32_16x16x32_bf16(a1,b0,acc[1][0],0,0,0);
        acc[1][1] = __builtin_amdgcn_mfma_f32_16x16x32_bf16(a1,b1,acc[1][1],0,0,0);
    }
}
// C/D layout: col = lane&15, row = (lane>>4)*4 + reg  (m89-verified)

// ---------------- downsample GEMM: xp(4096,256) @ wbd(128,256)^T + bias, silu, dual write
__global__ void k_gemm_down(const ushort* __restrict__ xp, const ushort* __restrict__ wd,
                            const float* __restrict__ bias, float* __restrict__ h){
    int w = threadIdx.x>>6, lane = threadIdx.x&63, rw = w>>1, cw = w&1;
    int m0 = blockIdx.x*64 + rw*32;
    int n0 = blockIdx.y*64 + cw*32;
    facc acc[2][2] = {};
    mm_core<256>(xp + (size_t)m0*256, wd + (size_t)n0*256, acc);
    int q = lane>>4, rr = lane&15;
    #pragma unroll
    for (int im=0; im<2; ++im)
    #pragma unroll
    for (int in=0; in<2; ++in){
        int col = n0 + in*16 + rr;
        float bv = bias[col];
        #pragma unroll
        for (int r2=0; r2<4; ++r2){
            int row = m0 + im*16 + q*4 + r2;
            int b = row >> 11, l = row & 2047;
            float v = siluf_(acc[im][in][r2] + bv);
            h[((size_t)(b*L + l))*D + col] = v;
            h[((size_t)((2+b)*L + (L-1-l)))*D + col] = v;
        }
    }
}

// ---------------- residual + layernorm -> bf16 hn
__global__ void k_resln(const float* __restrict__ curIn, float* __restrict__ res,
                        const float* __restrict__ lnw, const float* __restrict__ lnb,
                        ushort* __restrict__ hnb, int blk, int first){
    int l = blockIdx.x, s = blockIdx.y, d = threadIdx.x;
    int j = (s>>1)*3 + blk;
    int tb = s*L + l;
    float r = curIn[tb*D + d];
    if (!first) r += res[tb*D + d];
    res[tb*D + d] = r;
    __shared__ float red[128];
    red[d] = r; __syncthreads();
    for (int off=64; off; off>>=1){ if (d<off) red[d]+=red[d+off]; __syncthreads(); }
    float mean = red[0]*(1.f/128.f);
    __syncthreads();
    float c = r - mean;
    red[d] = c*c; __syncthreads();
    for (int off=64; off; off>>=1){ if (d<off) red[d]+=red[d+off]; __syncthreads(); }
    float var = red[0]*(1.f/128.f);
    float rstd = rsqrtf(var + 1e-5f);
    hnb[(size_t)tb*D + d] = f2bf(c*rstd*lnw[j*D + d] + lnb[j*D + d]);
}

// ---------------- in_proj GEMM: hnb(8192,128) @ wbi[j](512,128)^T -> xm | z (fp32)
__global__ void k_gemm_in(const ushort* __restrict__ hnb, const ushort* __restrict__ wbi,
                          float* __restrict__ xm, float* __restrict__ z, int blk){
    int w = threadIdx.x>>6, lane = threadIdx.x&63, rw = w>>1, cw = w&1;
    int m0 = blockIdx.x*64 + rw*32;
    int n0 = blockIdx.y*64 + cw*32;
    int dir = blockIdx.x >> 6;
    int j = dir*3 + blk;
    facc acc[2][2] = {};
    mm_core<128>(hnb + (size_t)m0*128, wbi + ((size_t)j*512 + n0)*128, acc);
    int q = lane>>4, rr = lane&15;
    #pragma unroll
    for (int im=0; im<2; ++im)
    #pragma unroll
    for (int in=0; in<2; ++in){
        int e = n0 + in*16 + rr;
        #pragma unroll
        for (int r2=0; r2<4; ++r2){
            int row = m0 + im*16 + q*4 + r2;
            float v = acc[im][in][r2];
            if (e < DI) xm[(size_t)row*DI + e] = v;
            else        z [(size_t)row*DI + (e-DI)] = v;
        }
    }
}

// ---------------- causal depthwise conv + silu -> xc fp32 + bf16
__global__ void k_conv(const float* __restrict__ xm, const float* __restrict__ cw,
                       const float* __restrict__ cb, float* __restrict__ xc,
                       ushort* __restrict__ xcb, int blk){
    int s = blockIdx.y; int j = (s>>1)*3 + blk;
    int l = blockIdx.x; int e = threadIdx.x;
    int sb = s*L;
    const float* w = cw + ((size_t)j*DI + e)*4;
    float acc = cb[j*DI + e];
    #pragma unroll
    for (int k=0;k<4;++k){
        int ll = l + k - 3;
        if (ll >= 0) acc += xm[(size_t)(sb+ll)*DI + e]*w[k];
    }
    float v = siluf_(acc);
    xc [(size_t)(sb+l)*DI + e] = v;
    xcb[(size_t)(sb+l)*DI + e] = f2bf(v);
}

// ---------------- x_proj GEMM: xcb(8192,256) @ wbx[j](64pad,256)^T -> dtr/Bc/Cc
__global__ void k_gemm_x(const ushort* __restrict__ xcb, const ushort* __restrict__ wbx,
                         float* __restrict__ dtr, float* __restrict__ Bc,
                         float* __restrict__ Cc, int blk){
    int w = threadIdx.x>>6, lane = threadIdx.x&63, rw = w>>1, cw = w&1;
    int m0 = blockIdx.x*64 + rw*32;
    int n0 = cw*32;
    int dir = blockIdx.x >> 6;
    int j = dir*3 + blk;
    facc acc[2][2] = {};
    mm_core<256>(xcb + (size_t)m0*256, wbx + ((size_t)j*64 + n0)*256, acc);
    int q = lane>>4, rr = lane&15;
    #pragma unroll
    for (int im=0; im<2; ++im)
    #pragma unroll
    for (int in=0; in<2; ++in){
        int col = n0 + in*16 + rr;
        #pragma unroll
        for (int r2=0; r2<4; ++r2){
            int row = m0 + im*16 + q*4 + r2;
            float v = acc[im][in][r2];
            if      (col < 8)  dtr[(size_t)row*RK + col] = v;
            else if (col < 24) Bc [(size_t)row*NS + (col-8)] = v;
            else if (col < 40) Cc [(size_t)row*NS + (col-24)] = v;
        }
    }
}

// ---------------- dt_proj + softplus (fp32, K=8)
__global__ void k_dtproj(const float* __restrict__ dtr, const float* __restrict__ Wdt,
                         const float* __restrict__ bdt, float* __restrict__ dt, int blk){
    int s = blockIdx.y; int j = (s>>1)*3 + blk;
    int l0 = blockIdx.x*TT;
    int e = threadIdx.x;
    __shared__ float rs[TT][RK];
    int tb0 = s*L + l0;
    for (int i = threadIdx.x; i < TT*RK; i += 256)
        rs[i>>3][i&7] = dtr[(size_t)(tb0 + (i>>3))*RK + (i&7)];
    __syncthreads();
    const float* wr = Wdt + ((size_t)j*DI + e)*RK;
    float wv[RK];
    #pragma unroll
    for (int r=0;r<RK;++r) wv[r] = wr[r];
    float bb = bdt[j*DI + e];
    for (int t=0;t<TT;++t){
        float acc = bb;
        #pragma unroll
        for (int r=0;r<RK;++r) acc += rs[t][r]*wv[r];
        dt[(size_t)(tb0+t)*DI + e] = (acc > 20.f) ? acc : log1pf(__expf(acc));
    }
}

// ---------------- scan phase 1: per-chunk summaries, thread-per-d, 16 n in regs
__global__ void k_scan1(const float* __restrict__ dt, const float* __restrict__ xcv,
                        const float* __restrict__ Bc, const float* __restrict__ A_log,
                        float* __restrict__ Aprod, float* __restrict__ Bend, int blk){
    // grid (NC, NSTREAM), block 256 (d)
    int c = blockIdx.x, s = blockIdx.y; int j = (s>>1)*3 + blk;
    int d = threadIdx.x;
    __shared__ float sB[CHUNK*NS];   // 256 floats, contiguous slab of Bc
    int base_tok = s*L + c*CHUNK;
    sB[d] = Bc[(size_t)base_tok*NS + d];
    float A[NS];
    const float* ar = A_log + ((size_t)j*DI + d)*NS;
    #pragma unroll
    for (int n=0;n<NS;++n) A[n] = -__expf(ar[n]);
    float ap[NS], hs[NS];
    #pragma unroll
    for (int n=0;n<NS;++n){ ap[n]=1.f; hs[n]=0.f; }
    __syncthreads();
    #pragma unroll 4
    for (int l=0;l<CHUNK;++l){
        int tb = base_tok + l;
        float dtv = dt[(size_t)tb*DI + d];
        float xv  = xcv[(size_t)tb*DI + d];
        float dbx = dtv*xv;
        #pragma unroll
        for (int n=0;n<NS;++n){
            float dA = __expf(dtv*A[n]);
            ap[n] *= dA;
            hs[n] = dA*hs[n] + dbx*sB[l*NS+n];
        }
    }
    size_t obase = ((size_t)(s*NC + c)*NS)*DI + d;
    #pragma unroll
    for (int n=0;n<NS;++n){
        Aprod[obase + (size_t)n*DI] = ap[n];
        Bend [obase + (size_t)n*DI] = hs[n];
    }
}

// ---------------- scan mid: fold chunk summaries sequentially; Bend becomes carry-in h0
__global__ void k_scanmid(const float* __restrict__ Aprod, float* __restrict__ Bend){
    // 16384 threads: tid = s*4096 + n*256 + d
    int tid = blockIdx.x*256 + threadIdx.x;
    int s = tid >> 12;
    int nd = tid & 4095;
    float h = 0.f;
    size_t idx = ((size_t)s*NC)*NS*DI + nd;
    float a = Aprod[idx], b = Bend[idx];
    for (int c=0;c<NC;++c){
        size_t nxt = idx + (size_t)NS*DI;
        float a2 = 0.f, b2 = 0.f;
        if (c+1 < NC){ a2 = Aprod[nxt]; b2 = Bend[nxt]; }
        Bend[idx] = h;            // carry INTO chunk c
        h = a*h + b;
        a = a2; b = b2; idx = nxt;
    }
}

// ---------------- scan phase 2: apply with carry-in, emit y; thread-per-d
__global__ void k_scan2(const float* __restrict__ dt, const float* __restrict__ xcv,
                        const float* __restrict__ Bc, const float* __restrict__ Cc,
                        const float* __restrict__ A_log, const float* __restrict__ h0,
                        float* __restrict__ y, int blk){
    int c = blockIdx.x, s = blockIdx.y; int j = (s>>1)*3 + blk;
    int d = threadIdx.x;
    __shared__ float sB[CHUNK*NS], sC[CHUNK*NS];
    int base_tok = s*L + c*CHUNK;
    sB[d] = Bc[(size_t)base_tok*NS + d];
    sC[d] = Cc[(size_t)base_tok*NS + d];
    float A[NS];
    const float* ar = A_log + ((size_t)j*DI + d)*NS;
    #pragma unroll
    for (int n=0;n<NS;++n) A[n] = -__expf(ar[n]);
    float hs[NS];
    size_t ibase = ((size_t)(s*NC + c)*NS)*DI + d;
    #pragma unroll
    for (int n=0;n<NS;++n) hs[n] = h0[ibase + (size_t)n*DI];
    __syncthreads();
    #pragma unroll 4
    for (int l=0;l<CHUNK;++l){
        int tb = base_tok + l;
        float dtv = dt[(size_t)tb*DI + d];
        float xv  = xcv[(size_t)tb*DI + d];
        float dbx = dtv*xv;
        float p = 0.f;
        #pragma unroll
        for (int n=0;n<NS;++n){
            float dA = __expf(dtv*A[n]);
            hs[n] = dA*hs[n] + dbx*sB[l*NS+n];
            p += hs[n]*sC[l*NS+n];
        }
        y[(size_t)tb*DI + d] = p;
    }
}

// ---------------- gate: g = (y + D*xc)*silu(z) -> bf16
__global__ void k_gate(const float* __restrict__ y, const float* __restrict__ xc,
                       const float* __restrict__ z, const float* __restrict__ Dp,
                       ushort* __restrict__ g, int blk){
    int idx = blockIdx.x*256 + threadIdx.x;
    int base = idx*4;
    int e  = base & 255;
    int s  = (base >> 8) >> 11;
    int j  = (s>>1)*3 + blk;
    float4 yv = *(const float4*)(y + base);
    float4 xv = *(const float4*)(xc + base);
    float4 zv = *(const float4*)(z + base);
    float4 dv = *(const float4*)(Dp + (size_t)j*DI + e);
    ushort4 o;
    o.x = f2bf((yv.x + dv.x*xv.x)*siluf_(zv.x));
    o.y = f2bf((yv.y + dv.y*xv.y)*siluf_(zv.y));
    o.z = f2bf((yv.z + dv.z*xv.z)*siluf_(zv.z));
    o.w = f2bf((yv.w + dv.w*xv.w)*siluf_(zv.w));
    *(ushort4*)(g + base) = o;
}

// ---------------- out_proj GEMM: g(8192,256) @ wbo[j](128,256)^T -> cur fp32
__global__ void k_gemm_out(const ushort* __restrict__ g, const ushort* __restrict__ wbo,
                           float* __restrict__ cur, int blk){
    int w = threadIdx.x>>6, lane = threadIdx.x&63, rw = w>>1, cw = w&1;
    int m0 = blockIdx.x*64 + rw*32;
    int n0 = blockIdx.y*64 + cw*32;
    int dir = blockIdx.x >> 6;
    int j = dir*3 + blk;
    facc acc[2][2] = {};
    mm_core<256>(g + (size_t)m0*256, wbo + ((size_t)j*128 + n0)*256, acc);
    int q = lane>>4, rr = lane&15;
    #pragma unroll
    for (int im=0; im<2; ++im)
    #pragma unroll
    for (int in=0; in<2; ++in){
        int col = n0 + in*16 + rr;
        #pragma unroll
        for (int r2=0; r2<4; ++r2){
            int row = m0 + im*16 + q*4 + r2;
            cur[(size_t)row*D + col] = acc[im][in][r2];
        }
    }
}

// ---------------- final combine
__global__ void k_final(const float* __restrict__ cur, const float* __restrict__ res,
                        float* __restrict__ out){
    int l = blockIdx.x, b = blockIdx.y, d = threadIdx.x;
    int tf = (b*L + l)*D + d;
    int tbk = ((2+b)*L + (L-1-l))*D + d;
    float f  = cur[tf] + res[tf];
    float bw = cur[tbk] + res[tbk];
    out[((size_t)(b*D + d))*L + l] = f + bw;
    out[(size_t)2*D*L + (size_t)(b*L + l)*D + d] = res[tf];
    out[(size_t)2*D*L + (size_t)((2+b)*L + l)*D + d] = res[((2+b)*L + l)*D + d];
}

extern "C" void kernel_launch(void* const* d_in, const int* in_sizes, int n_in,
                              void* d_out, int out_size, void* d_ws, size_t ws_size,
                              hipStream_t stream){
    const float* x         = (const float*)d_in[0];
    const float* convd_w   = (const float*)d_in[1];
    const float* convd_b   = (const float*)d_in[2];
    const float* ln_w      = (const float*)d_in[3];
    const float* ln_b      = (const float*)d_in[4];
    const float* in_proj_w = (const float*)d_in[5];
    const float* conv_w    = (const float*)d_in[6];
    const float* conv_b    = (const float*)d_in[7];
    const float* xproj_w   = (const float*)d_in[8];
    const float* dtproj_w  = (const float*)d_in[9];
    const float* dtproj_b  = (const float*)d_in[10];
    const float* A_log     = (const float*)d_in[11];
    const float* Dparam    = (const float*)d_in[12];
    const float* outproj_w = (const float*)d_in[13];

    float* ws = (float*)d_ws;
    const size_t SZ_D  = (size_t)TOK*D;    // 1,048,576 floats
    const size_t SZ_DI = (size_t)TOK*DI;   // 2,097,152 floats
    float* h     = ws; ws += SZ_D;
    float* res   = ws; ws += SZ_D;
    float* cur   = ws; ws += SZ_D;   // + hnreg: hosts Bend (8 MB) during scan
    float* hnreg = ws; ws += SZ_D;   // hosts hnb (2MB) + xp (2MB)
    float* xm    = ws; ws += SZ_DI;  // hosts Aprod (8 MB) during scan
    float* z     = ws; ws += SZ_DI;
    float* xc    = ws; ws += SZ_DI;
    float* dt    = ws; ws += SZ_DI;  // first 4MB re-used as g (bf16) after scan2
    float* y     = ws; ws += SZ_DI;  // first 4MB re-used as xcb (bf16) until scan2
    float* dtr   = ws; ws += (size_t)TOK*RK;
    float* Bc    = ws; ws += (size_t)TOK*NS;
    float* Cc    = ws; ws += (size_t)TOK*NS;
    ushort* wbd  = (ushort*)ws;                 // (128,256)       32768
    ushort* wbi  = wbd + 32768;                 // (6,512,128)    393216
    ushort* wbx  = wbi + 393216;                // (6,64,256) pad  98304
    ushort* wbo  = wbx + 98304;                 // (6,128,256)    196608

    ushort* hnb  = (ushort*)hnreg;
    ushort* xp   = hnb + (size_t)TOK*D;
    ushort* xcb  = (ushort*)y;
    ushort* g    = (ushort*)dt;
    // scan summaries: NSTREAM*NC*NS*DI = 2,097,152 floats each
    float* Aprod = xm;               // 8 MB, xm dead after k_conv
    float* Bend  = cur;              // spans cur+hnreg (contiguous 8 MB), dead window

    // weight conversions (cheap, every launch — graph-safe)
    k_cvt<<<128, 256, 0, stream>>>(convd_w, wbd, 32768);
    k_cvt<<<1536, 256, 0, stream>>>(in_proj_w, wbi, 393216);
    k_cvt<<<768, 256, 0, stream>>>(outproj_w, wbo, 196608);
    k_cvt_xw<<<384, 256, 0, stream>>>(xproj_w, wbx);

    k_patch<<<dim3(L/256, CIN, B), 256, 0, stream>>>(x, xp);
    k_gemm_down<<<dim3(64, 2), 256, 0, stream>>>(xp, wbd, convd_b, h);

    for (int blk = 0; blk < 3; ++blk){
        k_resln<<<dim3(L, NSTREAM), 128, 0, stream>>>(blk==0 ? h : cur, res, ln_w, ln_b, hnb, blk, blk==0);
        k_gemm_in<<<dim3(128, 8), 256, 0, stream>>>(hnb, wbi, xm, z, blk);
        k_conv<<<dim3(L, NSTREAM), 256, 0, stream>>>(xm, conv_w, conv_b, xc, xcb, blk);
        k_gemm_x<<<dim3(128, 1), 256, 0, stream>>>(xcb, wbx, dtr, Bc, Cc, blk);
        k_dtproj<<<dim3(L/TT, NSTREAM), 256, 0, stream>>>(dtr, dtproj_w, dtproj_b, dt, blk);
        k_scan1<<<dim3(NC, NSTREAM), 256, 0, stream>>>(dt, xc, Bc, A_log, Aprod, Bend, blk);
        k_scanmid<<<64, 256, 0, stream>>>(Aprod, Bend);
        k_scan2<<<dim3(NC, NSTREAM), 256, 0, stream>>>(dt, xc, Bc, Cc, A_log, Bend, y, blk);
        k_gate<<<2048, 256, 0, stream>>>(y, xc, z, Dparam, g, blk);
        k_gemm_out<<<dim3(128, 2), 256, 0, stream>>>(g, wbo, cur, blk);
    }

    k_final<<<dim3(L, B), 128, 0, stream>>>(cur, res, (float*)d_out);
}

// Round 5
// 362.704 us; speedup vs baseline: 8.4265x; 1.1055x over previous
//
#include <hip/hip_runtime.h>
#include <hip/hip_bf16.h>
#include <math.h>

// Problem constants
#define B    2
#define CIN  64
#define LIN  8192
#define L    2048
#define D    128
#define DI   256
#define NS   16
#define RK   8
#define NSTREAM 4       // (dir, batch): s = dir*2 + b
#define CHUNK 16
#define NC   (L/CHUNK)  // 128
#define TOK  (NSTREAM*L) // 8192 token-rows

typedef short  bfrag __attribute__((ext_vector_type(8)));  // 8 bf16 (4 VGPRs)
typedef float  facc  __attribute__((ext_vector_type(4)));  // 4 fp32 acc

__device__ __forceinline__ float sigmoidf_(float x){ return 1.f/(1.f+__expf(-x)); }
__device__ __forceinline__ float siluf_(float x){ return x*sigmoidf_(x); }
__device__ __forceinline__ ushort f2bf(float f){
    unsigned u = __float_as_uint(f);
    u += 0x7fffu + ((u>>16)&1u);       // round-to-nearest-even
    return (ushort)(u>>16);
}
__device__ __forceinline__ float softplusf_(float t){
    return (t > 20.f) ? t : __logf(1.f + __expf(t));
}

// ---------------- all weight conversions in one kernel
// dst layout: wbd(32768) | wbi(393216) | wbo(196608) | wbx(98304, 40->64 pad)
__global__ void k_cvtall(const float* __restrict__ cw, const float* __restrict__ ipw,
                         const float* __restrict__ opw, const float* __restrict__ xpw,
                         ushort* __restrict__ dst){
    int i = blockIdx.x*256 + threadIdx.x;   // 720896 total
    ushort v;
    if (i < 32768)       v = f2bf(cw[i]);
    else if (i < 425984) v = f2bf(ipw[i-32768]);
    else if (i < 622592) v = f2bf(opw[i-425984]);
    else {
        int t = i - 622592;
        int k = t & 255, nr = (t>>8) & 63, j = t>>14;
        v = (nr < 40) ? f2bf(xpw[((size_t)j*40 + nr)*256 + k]) : (ushort)0;
    }
    dst[i] = v;
}

// ---------------- pack downsample patches: x (B,CIN,LIN) -> xp (B*L, CIN*4) bf16
__global__ void k_patch(const float* __restrict__ x, ushort* __restrict__ xp){
    int l = blockIdx.x*256 + threadIdx.x;
    int c = blockIdx.y, b = blockIdx.z;
    float4 v = *(const float4*)(x + ((size_t)(b*CIN + c))*LIN + 4*l);
    ushort4 o; o.x=f2bf(v.x); o.y=f2bf(v.y); o.z=f2bf(v.z); o.w=f2bf(v.w);
    *(ushort4*)(xp + ((size_t)(b*L + l))*(CIN*4) + c*4) = o;
}

// ---------------- MFMA core: 32x32 wave tile of C = X(M,K) @ W(N,K)^T
template<int K>
__device__ __forceinline__ void mm_core(const ushort* __restrict__ X,
                                        const ushort* __restrict__ Wt,
                                        facc (&acc)[2][2]){
    const int lane = threadIdx.x & 63;
    const int q = lane >> 4, r = lane & 15;
    const bfrag* xa0 = (const bfrag*)(X  + (size_t)r*K      + q*8);
    const bfrag* xa1 = (const bfrag*)(X  + (size_t)(r+16)*K + q*8);
    const bfrag* wb0 = (const bfrag*)(Wt + (size_t)r*K      + q*8);
    const bfrag* wb1 = (const bfrag*)(Wt + (size_t)(r+16)*K + q*8);
    #pragma unroll
    for (int kb = 0; kb < K/32; ++kb){
        bfrag a0 = xa0[kb*4], a1 = xa1[kb*4];
        bfrag b0 = wb0[kb*4], b1 = wb1[kb*4];
        acc[0][0] = __builtin_amdgcn_mfma_f32_16x16x32_bf16(a0,b0,acc[0][0],0,0,0);
        acc[0][1] = __builtin_amdgcn_mfma_f32_16x16x32_bf16(a0,b1,acc[0][1],0,0,0);
        acc[1][0] = __builtin_amdgcn_mfma_f32_16x16x32_bf16(a1,b0,acc[1][0],0,0,0);
        acc[1][1] = __builtin_amdgcn_mfma_f32_16x16x32_bf16(a1,b1,acc[1][1],0,0,0);
    }
}
// C/D layout: col = lane&15, row = (lane>>4)*4 + reg  (m89-verified)

// ---------------- downsample GEMM: xp(4096,256) @ wbd(128,256)^T + bias, silu, dual write
__global__ void k_gemm_down(const ushort* __restrict__ xp, const ushort* __restrict__ wd,
                            const float* __restrict__ bias, float* __restrict__ h){
    int w = threadIdx.x>>6, lane = threadIdx.x&63, rw = w>>1, cw = w&1;
    int m0 = blockIdx.x*64 + rw*32;
    int n0 = blockIdx.y*64 + cw*32;
    facc acc[2][2] = {};
    mm_core<256>(xp + (size_t)m0*256, wd + (size_t)n0*256, acc);
    int q = lane>>4, rr = lane&15;
    #pragma unroll
    for (int im=0; im<2; ++im)
    #pragma unroll
    for (int in=0; in<2; ++in){
        int col = n0 + in*16 + rr;
        float bv = bias[col];
        #pragma unroll
        for (int r2=0; r2<4; ++r2){
            int row = m0 + im*16 + q*4 + r2;
            int b = row >> 11, l = row & 2047;
            float v = siluf_(acc[im][in][r2] + bv);
            h[((size_t)(b*L + l))*D + col] = v;
            h[((size_t)((2+b)*L + (L-1-l)))*D + col] = v;
        }
    }
}

// ---------------- residual + layernorm -> bf16 hn (2 tokens/block, shuffle reduce)
__global__ void k_resln(const float* __restrict__ curIn, float* __restrict__ res,
                        const float* __restrict__ lnw, const float* __restrict__ lnb,
                        ushort* __restrict__ hnb, int blk, int first){
    // grid (L/2, NSTREAM), block 256
    int t = threadIdx.x >> 7;       // token within block
    int d = threadIdx.x & 127;
    int s = blockIdx.y; int j = (s>>1)*3 + blk;
    int l = blockIdx.x*2 + t;
    int tb = s*L + l;
    float r = curIn[(size_t)tb*D + d];
    if (!first) r += res[(size_t)tb*D + d];
    res[(size_t)tb*D + d] = r;
    float s1 = r, s2 = r*r;
    #pragma unroll
    for (int off=1; off<=32; off<<=1){
        s1 += __shfl_xor(s1, off);
        s2 += __shfl_xor(s2, off);
    }
    __shared__ float ps[4][2];
    int w = threadIdx.x >> 6;
    if ((threadIdx.x & 63) == 0){ ps[w][0]=s1; ps[w][1]=s2; }
    __syncthreads();
    int w0 = t*2;
    float S1 = ps[w0][0]+ps[w0+1][0];
    float S2 = ps[w0][1]+ps[w0+1][1];
    float mean = S1*(1.f/128.f);
    float var  = S2*(1.f/128.f) - mean*mean;
    float rstd = rsqrtf(var + 1e-5f);
    hnb[(size_t)tb*D + d] = f2bf((r-mean)*rstd*lnw[j*D + d] + lnb[j*D + d]);
}

// ---------------- in_proj GEMM: hnb(8192,128) @ wbi[j](512,128)^T -> xm | z (fp32)
__global__ void k_gemm_in(const ushort* __restrict__ hnb, const ushort* __restrict__ wbi,
                          float* __restrict__ xm, float* __restrict__ z, int blk){
    int w = threadIdx.x>>6, lane = threadIdx.x&63, rw = w>>1, cw = w&1;
    int m0 = blockIdx.x*64 + rw*32;
    int n0 = blockIdx.y*64 + cw*32;
    int dir = blockIdx.x >> 6;
    int j = dir*3 + blk;
    facc acc[2][2] = {};
    mm_core<128>(hnb + (size_t)m0*128, wbi + ((size_t)j*512 + n0)*128, acc);
    int q = lane>>4, rr = lane&15;
    #pragma unroll
    for (int im=0; im<2; ++im)
    #pragma unroll
    for (int in=0; in<2; ++in){
        int e = n0 + in*16 + rr;
        #pragma unroll
        for (int r2=0; r2<4; ++r2){
            int row = m0 + im*16 + q*4 + r2;
            float v = acc[im][in][r2];
            if (e < DI) xm[(size_t)row*DI + e] = v;
            else        z [(size_t)row*DI + (e-DI)] = v;
        }
    }
}

// ---------------- causal depthwise conv + silu -> xc fp32 + bf16
__global__ void k_conv(const float* __restrict__ xm, const float* __restrict__ cw,
                       const float* __restrict__ cb, float* __restrict__ xc,
                       ushort* __restrict__ xcb, int blk){
    int s = blockIdx.y; int j = (s>>1)*3 + blk;
    int l = blockIdx.x; int e = threadIdx.x;
    int sb = s*L;
    const float* w = cw + ((size_t)j*DI + e)*4;
    float acc = cb[j*DI + e];
    #pragma unroll
    for (int k=0;k<4;++k){
        int ll = l + k - 3;
        if (ll >= 0) acc += xm[(size_t)(sb+ll)*DI + e]*w[k];
    }
    float v = siluf_(acc);
    xc [(size_t)(sb+l)*DI + e] = v;
    xcb[(size_t)(sb+l)*DI + e] = f2bf(v);
}

// ---------------- x_proj GEMM: xcb(8192,256) @ wbx[j](64pad,256)^T -> dtr/Bc/Cc
__global__ void k_gemm_x(const ushort* __restrict__ xcb, const ushort* __restrict__ wbx,
                         float* __restrict__ dtr, float* __restrict__ Bc,
                         float* __restrict__ Cc, int blk){
    int w = threadIdx.x>>6, lane = threadIdx.x&63, rw = w>>1, cw = w&1;
    int m0 = blockIdx.x*64 + rw*32;
    int n0 = cw*32;
    int dir = blockIdx.x >> 6;
    int j = dir*3 + blk;
    facc acc[2][2] = {};
    mm_core<256>(xcb + (size_t)m0*256, wbx + ((size_t)j*64 + n0)*256, acc);
    int q = lane>>4, rr = lane&15;
    #pragma unroll
    for (int im=0; im<2; ++im)
    #pragma unroll
    for (int in=0; in<2; ++in){
        int col = n0 + in*16 + rr;
        #pragma unroll
        for (int r2=0; r2<4; ++r2){
            int row = m0 + im*16 + q*4 + r2;
            float v = acc[im][in][r2];
            if      (col < 8)  dtr[(size_t)row*RK + col] = v;
            else if (col < 24) Bc [(size_t)row*NS + (col-8)] = v;
            else if (col < 40) Cc [(size_t)row*NS + (col-24)] = v;
        }
    }
}

// ---------------- scan phase 1: fused dt_proj+softplus, per-chunk affine summaries
__global__ void k_scan1(const float* __restrict__ dtr, const float* __restrict__ xcv,
                        const float* __restrict__ Bc, const float* __restrict__ A_log,
                        const float* __restrict__ Wdt, const float* __restrict__ bdt,
                        float* __restrict__ Aprod, float* __restrict__ Bend, int blk){
    // grid (NC, NSTREAM), block 256 (d)
    int c = blockIdx.x, s = blockIdx.y; int j = (s>>1)*3 + blk;
    int d = threadIdx.x;
    __shared__ float sB[CHUNK*NS];     // 256
    __shared__ float sdtr[CHUNK*RK];   // 128
    int base_tok = s*L + c*CHUNK;
    sB[d] = Bc[(size_t)base_tok*NS + d];
    if (d < CHUNK*RK) sdtr[d] = dtr[(size_t)base_tok*RK + d];
    float A[NS];
    const float* ar = A_log + ((size_t)j*DI + d)*NS;
    #pragma unroll
    for (int n=0;n<NS;++n) A[n] = -__expf(ar[n]);
    float wv[RK];
    const float* wr = Wdt + ((size_t)j*DI + d)*RK;
    #pragma unroll
    for (int r=0;r<RK;++r) wv[r] = wr[r];
    float bb = bdt[j*DI + d];
    float ap[NS], hs[NS];
    #pragma unroll
    for (int n=0;n<NS;++n){ ap[n]=1.f; hs[n]=0.f; }
    __syncthreads();
    #pragma unroll 4
    for (int l=0;l<CHUNK;++l){
        int tb = base_tok + l;
        float t = bb;
        #pragma unroll
        for (int r=0;r<RK;++r) t += sdtr[l*RK+r]*wv[r];
        float dtv = softplusf_(t);
        float xv  = xcv[(size_t)tb*DI + d];
        float dbx = dtv*xv;
        #pragma unroll
        for (int n=0;n<NS;++n){
            float dA = __expf(dtv*A[n]);
            ap[n] *= dA;
            hs[n] = dA*hs[n] + dbx*sB[l*NS+n];
        }
    }
    size_t obase = ((size_t)(s*NC + c)*NS)*DI + d;
    #pragma unroll
    for (int n=0;n<NS;++n){
        Aprod[obase + (size_t)n*DI] = ap[n];
        Bend [obase + (size_t)n*DI] = hs[n];
    }
}

// ---------------- scan mid: fold chunk summaries; Bend becomes carry-in h0
// software-pipelined: 16 independent loads per group, then fold
__global__ void k_scanmid(const float* __restrict__ Aprod, float* __restrict__ Bend){
    // 64 blocks x 256: tid = s*4096 + n*256 + d
    int tid = blockIdx.x*256 + threadIdx.x;
    int s = tid >> 12;
    int nd = tid & 4095;
    const size_t stride = (size_t)NS*DI;
    size_t base = ((size_t)s*NC)*stride + nd;
    float h = 0.f;
    for (int c0=0; c0<NC; c0+=16){
        float a[16], b[16];
        #pragma unroll
        for (int i=0;i<16;++i){
            a[i] = Aprod[base + (size_t)(c0+i)*stride];
            b[i] = Bend [base + (size_t)(c0+i)*stride];
        }
        #pragma unroll
        for (int i=0;i<16;++i){
            Bend[base + (size_t)(c0+i)*stride] = h;  // carry INTO chunk c0+i
            h = a[i]*h + b[i];
        }
    }
}

// ---------------- scan phase 2: fused dt recompute + gate; emits g (bf16)
__global__ void k_scan2(const float* __restrict__ dtr, const float* __restrict__ xcv,
                        const float* __restrict__ Bc, const float* __restrict__ Cc,
                        const float* __restrict__ A_log,
                        const float* __restrict__ Wdt, const float* __restrict__ bdt,
                        const float* __restrict__ h0, const float* __restrict__ z,
                        const float* __restrict__ Dp, ushort* __restrict__ g, int blk){
    int c = blockIdx.x, s = blockIdx.y; int j = (s>>1)*3 + blk;
    int d = threadIdx.x;
    __shared__ float sB[CHUNK*NS], sC[CHUNK*NS];
    __shared__ float sdtr[CHUNK*RK];
    int base_tok = s*L + c*CHUNK;
    sB[d] = Bc[(size_t)base_tok*NS + d];
    sC[d] = Cc[(size_t)base_tok*NS + d];
    if (d < CHUNK*RK) sdtr[d] = dtr[(size_t)base_tok*RK + d];
    float A[NS];
    const float* ar = A_log + ((size_t)j*DI + d)*NS;
    #pragma unroll
    for (int n=0;n<NS;++n) A[n] = -__expf(ar[n]);
    float wv[RK];
    const float* wr = Wdt + ((size_t)j*DI + d)*RK;
    #pragma unroll
    for (int r=0;r<RK;++r) wv[r] = wr[r];
    float bb = bdt[j*DI + d];
    float Dpd = Dp[j*DI + d];
    float hs[NS];
    size_t ibase = ((size_t)(s*NC + c)*NS)*DI + d;
    #pragma unroll
    for (int n=0;n<NS;++n) hs[n] = h0[ibase + (size_t)n*DI];
    __syncthreads();
    #pragma unroll 4
    for (int l=0;l<CHUNK;++l){
        int tb = base_tok + l;
        float t = bb;
        #pragma unroll
        for (int r=0;r<RK;++r) t += sdtr[l*RK+r]*wv[r];
        float dtv = softplusf_(t);
        float xv  = xcv[(size_t)tb*DI + d];
        float dbx = dtv*xv;
        float p = 0.f;
        #pragma unroll
        for (int n=0;n<NS;++n){
            float dA = __expf(dtv*A[n]);
            hs[n] = dA*hs[n] + dbx*sB[l*NS+n];
            p += hs[n]*sC[l*NS+n];
        }
        float zv = z[(size_t)tb*DI + d];
        g[(size_t)tb*DI + d] = f2bf((p + Dpd*xv)*siluf_(zv));
    }
}

// ---------------- out_proj GEMM: g(8192,256) @ wbo[j](128,256)^T -> cur fp32
__global__ void k_gemm_out(const ushort* __restrict__ g, const ushort* __restrict__ wbo,
                           float* __restrict__ cur, int blk){
    int w = threadIdx.x>>6, lane = threadIdx.x&63, rw = w>>1, cw = w&1;
    int m0 = blockIdx.x*64 + rw*32;
    int n0 = blockIdx.y*64 + cw*32;
    int dir = blockIdx.x >> 6;
    int j = dir*3 + blk;
    facc acc[2][2] = {};
    mm_core<256>(g + (size_t)m0*256, wbo + ((size_t)j*128 + n0)*256, acc);
    int q = lane>>4, rr = lane&15;
    #pragma unroll
    for (int im=0; im<2; ++im)
    #pragma unroll
    for (int in=0; in<2; ++in){
        int col = n0 + in*16 + rr;
        #pragma unroll
        for (int r2=0; r2<4; ++r2){
            int row = m0 + im*16 + q*4 + r2;
            cur[(size_t)row*D + col] = acc[im][in][r2];
        }
    }
}

// ---------------- final combine
__global__ void k_final(const float* __restrict__ cur, const float* __restrict__ res,
                        float* __restrict__ out){
    int l = blockIdx.x, b = blockIdx.y, d = threadIdx.x;
    int tf = (b*L + l)*D + d;
    int tbk = ((2+b)*L + (L-1-l))*D + d;
    float f  = cur[tf] + res[tf];
    float bw = cur[tbk] + res[tbk];
    out[((size_t)(b*D + d))*L + l] = f + bw;
    out[(size_t)2*D*L + (size_t)(b*L + l)*D + d] = res[tf];
    out[(size_t)2*D*L + (size_t)((2+b)*L + l)*D + d] = res[((2+b)*L + l)*D + d];
}

extern "C" void kernel_launch(void* const* d_in, const int* in_sizes, int n_in,
                              void* d_out, int out_size, void* d_ws, size_t ws_size,
                              hipStream_t stream){
    const float* x         = (const float*)d_in[0];
    const float* convd_w   = (const float*)d_in[1];
    const float* convd_b   = (const float*)d_in[2];
    const float* ln_w      = (const float*)d_in[3];
    const float* ln_b      = (const float*)d_in[4];
    const float* in_proj_w = (const float*)d_in[5];
    const float* conv_w    = (const float*)d_in[6];
    const float* conv_b    = (const float*)d_in[7];
    const float* xproj_w   = (const float*)d_in[8];
    const float* dtproj_w  = (const float*)d_in[9];
    const float* dtproj_b  = (const float*)d_in[10];
    const float* A_log     = (const float*)d_in[11];
    const float* Dparam    = (const float*)d_in[12];
    const float* outproj_w = (const float*)d_in[13];

    float* ws = (float*)d_ws;
    const size_t SZ_D  = (size_t)TOK*D;    // 1,048,576 floats
    const size_t SZ_DI = (size_t)TOK*DI;   // 2,097,152 floats
    float* h     = ws; ws += SZ_D;
    float* res   = ws; ws += SZ_D;
    float* cur   = ws; ws += SZ_D;   // + hnreg: hosts Bend (8 MB) during scan
    float* hnreg = ws; ws += SZ_D;   // hosts hnb (2MB) + xp (2MB)
    float* xm    = ws; ws += SZ_DI;  // hosts Aprod (8 MB) during scan
    float* z     = ws; ws += SZ_DI;
    float* xc    = ws; ws += SZ_DI;
    float* gbuf  = ws; ws += SZ_DI;  // first 4MB used as g (bf16)
    float* y     = ws; ws += SZ_DI;  // first 4MB used as xcb (bf16)
    float* dtr   = ws; ws += (size_t)TOK*RK;
    float* Bc    = ws; ws += (size_t)TOK*NS;
    float* Cc    = ws; ws += (size_t)TOK*NS;
    ushort* wall = (ushort*)ws;                 // packed bf16 weights
    ushort* wbd  = wall;                        // (128,256)       32768
    ushort* wbi  = wall + 32768;                // (6,512,128)    393216
    ushort* wbo  = wall + 425984;               // (6,128,256)    196608
    ushort* wbx  = wall + 622592;               // (6,64,256) pad  98304

    ushort* hnb  = (ushort*)hnreg;
    ushort* xp   = hnb + (size_t)TOK*D;
    ushort* xcb  = (ushort*)y;
    ushort* g    = (ushort*)gbuf;
    // scan summaries: NSTREAM*NC*NS*DI = 2,097,152 floats each
    float* Aprod = xm;               // xm dead after k_conv
    float* Bend  = cur;              // spans cur+hnreg (contiguous 8 MB), dead window

    k_cvtall<<<2816, 256, 0, stream>>>(convd_w, in_proj_w, outproj_w, xproj_w, wall);

    k_patch<<<dim3(L/256, CIN, B), 256, 0, stream>>>(x, xp);
    k_gemm_down<<<dim3(64, 2), 256, 0, stream>>>(xp, wbd, convd_b, h);

    for (int blk = 0; blk < 3; ++blk){
        k_resln<<<dim3(L/2, NSTREAM), 256, 0, stream>>>(blk==0 ? h : cur, res, ln_w, ln_b, hnb, blk, blk==0);
        k_gemm_in<<<dim3(128, 8), 256, 0, stream>>>(hnb, wbi, xm, z, blk);
        k_conv<<<dim3(L, NSTREAM), 256, 0, stream>>>(xm, conv_w, conv_b, xc, xcb, blk);
        k_gemm_x<<<dim3(128, 1), 256, 0, stream>>>(xcb, wbx, dtr, Bc, Cc, blk);
        k_scan1<<<dim3(NC, NSTREAM), 256, 0, stream>>>(dtr, xc, Bc, A_log, dtproj_w, dtproj_b, Aprod, Bend, blk);
        k_scanmid<<<64, 256, 0, stream>>>(Aprod, Bend);
        k_scan2<<<dim3(NC, NSTREAM), 256, 0, stream>>>(dtr, xc, Bc, Cc, A_log, dtproj_w, dtproj_b, Bend, z, Dparam, g, blk);
        k_gemm_out<<<dim3(128, 2), 256, 0, stream>>>(g, wbo, cur, blk);
    }

    k_final<<<dim3(L, B), 128, 0, stream>>>(cur, res, (float*)d_out);
}

// Round 6
// 346.546 us; speedup vs baseline: 8.8194x; 1.0466x over previous
//
#include <hip/hip_runtime.h>
#include <hip/hip_bf16.h>
#include <math.h>

// Problem constants
#define B    2
#define CIN  64
#define LIN  8192
#define L    2048
#define D    128
#define DI   256
#define NS   16
#define RK   8
#define NSTREAM 4       // (dir, batch): s = dir*2 + b
#define CHUNK 16
#define NC   (L/CHUNK)  // 128
#define TOK  (NSTREAM*L) // 8192 token-rows

typedef short  bfrag __attribute__((ext_vector_type(8)));  // 8 bf16 (4 VGPRs)
typedef float  facc  __attribute__((ext_vector_type(4)));  // 4 fp32 acc

__device__ __forceinline__ float sigmoidf_(float x){ return 1.f/(1.f+__expf(-x)); }
__device__ __forceinline__ float siluf_(float x){ return x*sigmoidf_(x); }
__device__ __forceinline__ ushort f2bf(float f){
    unsigned u = __float_as_uint(f);
    u += 0x7fffu + ((u>>16)&1u);       // round-to-nearest-even
    return (ushort)(u>>16);
}
__device__ __forceinline__ float softplusf_(float t){
    return (t > 20.f) ? t : __logf(1.f + __expf(t));
}

// ---------------- all weight conversions in one kernel
// dst layout: wbd(32768) | wbi(393216) | wbo(196608) | wbx(98304, 40->64 pad)
__global__ void k_cvtall(const float* __restrict__ cw, const float* __restrict__ ipw,
                         const float* __restrict__ opw, const float* __restrict__ xpw,
                         ushort* __restrict__ dst){
    int i = blockIdx.x*256 + threadIdx.x;   // 720896 total
    ushort v;
    if (i < 32768)       v = f2bf(cw[i]);
    else if (i < 425984) v = f2bf(ipw[i-32768]);
    else if (i < 622592) v = f2bf(opw[i-425984]);
    else {
        int t = i - 622592;
        int k = t & 255, nr = (t>>8) & 63, j = t>>14;
        v = (nr < 40) ? f2bf(xpw[((size_t)j*40 + nr)*256 + k]) : (ushort)0;
    }
    dst[i] = v;
}

// ---------------- pack downsample patches: x (B,CIN,LIN) -> xp (B*L, CIN*4) bf16
__global__ void k_patch(const float* __restrict__ x, ushort* __restrict__ xp){
    int l = blockIdx.x*256 + threadIdx.x;
    int c = blockIdx.y, b = blockIdx.z;
    float4 v = *(const float4*)(x + ((size_t)(b*CIN + c))*LIN + 4*l);
    ushort4 o; o.x=f2bf(v.x); o.y=f2bf(v.y); o.z=f2bf(v.z); o.w=f2bf(v.w);
    *(ushort4*)(xp + ((size_t)(b*L + l))*(CIN*4) + c*4) = o;
}

// ---------------- MFMA core (global A): 32x32 wave tile of C = X(M,K) @ W(N,K)^T
template<int K>
__device__ __forceinline__ void mm_core(const ushort* __restrict__ X,
                                        const ushort* __restrict__ Wt,
                                        facc (&acc)[2][2]){
    const int lane = threadIdx.x & 63;
    const int q = lane >> 4, r = lane & 15;
    const bfrag* xa0 = (const bfrag*)(X  + (size_t)r*K      + q*8);
    const bfrag* xa1 = (const bfrag*)(X  + (size_t)(r+16)*K + q*8);
    const bfrag* wb0 = (const bfrag*)(Wt + (size_t)r*K      + q*8);
    const bfrag* wb1 = (const bfrag*)(Wt + (size_t)(r+16)*K + q*8);
    #pragma unroll
    for (int kb = 0; kb < K/32; ++kb){
        bfrag a0 = xa0[kb*4], a1 = xa1[kb*4];
        bfrag b0 = wb0[kb*4], b1 = wb1[kb*4];
        acc[0][0] = __builtin_amdgcn_mfma_f32_16x16x32_bf16(a0,b0,acc[0][0],0,0,0);
        acc[0][1] = __builtin_amdgcn_mfma_f32_16x16x32_bf16(a0,b1,acc[0][1],0,0,0);
        acc[1][0] = __builtin_amdgcn_mfma_f32_16x16x32_bf16(a1,b0,acc[1][0],0,0,0);
        acc[1][1] = __builtin_amdgcn_mfma_f32_16x16x32_bf16(a1,b1,acc[1][1],0,0,0);
    }
}
// C/D layout: col = lane&15, row = (lane>>4)*4 + reg  (m89-verified)

// ---------------- downsample GEMM: xp(4096,256) @ wbd(128,256)^T + bias, silu, dual write
__global__ void k_gemm_down(const ushort* __restrict__ xp, const ushort* __restrict__ wd,
                            const float* __restrict__ bias, float* __restrict__ h){
    int w = threadIdx.x>>6, lane = threadIdx.x&63, rw = w>>1, cw = w&1;
    int m0 = blockIdx.x*64 + rw*32;
    int n0 = blockIdx.y*64 + cw*32;
    facc acc[2][2] = {};
    mm_core<256>(xp + (size_t)m0*256, wd + (size_t)n0*256, acc);
    int q = lane>>4, rr = lane&15;
    #pragma unroll
    for (int im=0; im<2; ++im)
    #pragma unroll
    for (int in=0; in<2; ++in){
        int col = n0 + in*16 + rr;
        float bv = bias[col];
        #pragma unroll
        for (int r2=0; r2<4; ++r2){
            int row = m0 + im*16 + q*4 + r2;
            int b = row >> 11, l = row & 2047;
            float v = siluf_(acc[im][in][r2] + bv);
            h[((size_t)(b*L + l))*D + col] = v;
            h[((size_t)((2+b)*L + (L-1-l)))*D + col] = v;
        }
    }
}

// ---------------- FUSED residual+LN+in_proj GEMM
// grid (TOK/64, 8), block 256. Each block: 64 tokens, 64 output cols.
// LN done redundantly per y-block; only y==0 persists res (ping-pong, no race).
__global__ void k_fused_in(const float* __restrict__ curIn, const float* __restrict__ resIn,
                           float* __restrict__ resOut,
                           const float* __restrict__ lnw, const float* __restrict__ lnb,
                           const ushort* __restrict__ wbi,
                           float* __restrict__ xm, float* __restrict__ z, int blk, int first){
    __shared__ ushort sh[64*136];   // 64 tokens x 128 bf16, row stride 136
    int m0 = blockIdx.x*64;
    int s = m0 >> 11; int j = (s>>1)*3 + blk;
    int tid = threadIdx.x;
    int t = tid >> 2, sub = tid & 3;       // token, 32-elem group
    size_t rowoff = (size_t)(m0 + t)*D + sub*32;
    float4 v[8];
    const float4* cp = (const float4*)(curIn + rowoff);
    #pragma unroll
    for (int i=0;i<8;++i) v[i] = cp[i];
    if (!first){
        const float4* rp = (const float4*)(resIn + rowoff);
        #pragma unroll
        for (int i=0;i<8;++i){ float4 rv = rp[i]; v[i].x+=rv.x; v[i].y+=rv.y; v[i].z+=rv.z; v[i].w+=rv.w; }
    }
    if (blockIdx.y == 0){
        float4* ro = (float4*)(resOut + rowoff);
        #pragma unroll
        for (int i=0;i<8;++i) ro[i] = v[i];
    }
    float s1 = 0.f, s2 = 0.f;
    #pragma unroll
    for (int i=0;i<8;++i){
        s1 += v[i].x + v[i].y + v[i].z + v[i].w;
        s2 += v[i].x*v[i].x + v[i].y*v[i].y + v[i].z*v[i].z + v[i].w*v[i].w;
    }
    s1 += __shfl_xor(s1, 1); s2 += __shfl_xor(s2, 1);
    s1 += __shfl_xor(s1, 2); s2 += __shfl_xor(s2, 2);
    float mean = s1*(1.f/128.f);
    float var  = s2*(1.f/128.f) - mean*mean;
    float rstd = rsqrtf(var + 1e-5f);
    const float4* lwp = (const float4*)(lnw + j*D + sub*32);
    const float4* lbp = (const float4*)(lnb + j*D + sub*32);
    #pragma unroll
    for (int i=0;i<8;++i){
        float4 lw = lwp[i], lb = lbp[i];
        ushort4 o;
        o.x = f2bf((v[i].x-mean)*rstd*lw.x + lb.x);
        o.y = f2bf((v[i].y-mean)*rstd*lw.y + lb.y);
        o.z = f2bf((v[i].z-mean)*rstd*lw.z + lb.z);
        o.w = f2bf((v[i].w-mean)*rstd*lw.w + lb.w);
        *(ushort4*)&sh[t*136 + sub*32 + i*4] = o;
    }
    __syncthreads();
    // GEMM: 64x64 from LDS A, global B
    int w = tid>>6, lane = tid&63, rw = w>>1, cw = w&1;
    int q = lane>>4, r = lane&15;
    int n0 = blockIdx.y*64 + cw*32;
    const ushort* b0p = wbi + ((size_t)j*512 + n0 + r)*128 + q*8;
    const ushort* b1p = b0p + (size_t)16*128;
    facc acc[2][2] = {};
    #pragma unroll
    for (int kb=0; kb<4; ++kb){
        bfrag a0 = *(bfrag*)&sh[(rw*32 + r)*136 + kb*32 + q*8];
        bfrag a1 = *(bfrag*)&sh[(rw*32 + 16 + r)*136 + kb*32 + q*8];
        bfrag b0 = *(const bfrag*)(b0p + kb*32);
        bfrag b1 = *(const bfrag*)(b1p + kb*32);
        acc[0][0] = __builtin_amdgcn_mfma_f32_16x16x32_bf16(a0,b0,acc[0][0],0,0,0);
        acc[0][1] = __builtin_amdgcn_mfma_f32_16x16x32_bf16(a0,b1,acc[0][1],0,0,0);
        acc[1][0] = __builtin_amdgcn_mfma_f32_16x16x32_bf16(a1,b0,acc[1][0],0,0,0);
        acc[1][1] = __builtin_amdgcn_mfma_f32_16x16x32_bf16(a1,b1,acc[1][1],0,0,0);
    }
    #pragma unroll
    for (int im=0; im<2; ++im)
    #pragma unroll
    for (int in=0; in<2; ++in){
        int e = n0 + in*16 + r;
        #pragma unroll
        for (int r2=0; r2<4; ++r2){
            int row = m0 + rw*32 + im*16 + q*4 + r2;
            float vv = acc[im][in][r2];
            if (e < DI) xm[(size_t)row*DI + e] = vv;
            else        z [(size_t)row*DI + (e-DI)] = vv;
        }
    }
}

// ---------------- FUSED causal conv + silu + x_proj GEMM
// grid (TOK/32), block 256. Each block: 32 tokens; conv thread-per-d, then 32x64 GEMM.
__global__ void k_convx(const float* __restrict__ xm, const float* __restrict__ cw,
                        const float* __restrict__ cb, const ushort* __restrict__ wbx,
                        float* __restrict__ xc, float* __restrict__ dtr,
                        float* __restrict__ Bc, float* __restrict__ Cc, int blk){
    __shared__ ushort sx[32*264];   // 32 tokens x 256 bf16, row stride 264
    int m0 = blockIdx.x*32;
    int s = m0 >> 11; int j = (s>>1)*3 + blk;
    int sl0 = m0 & 2047;            // stream-local start token
    int d = threadIdx.x;
    const float* w4 = cw + ((size_t)j*DI + d)*4;
    float w0=w4[0], w1=w4[1], w2=w4[2], w3=w4[3];
    float bb = cb[j*DI + d];
    float xm1=0.f, xm2=0.f, xm3=0.f;
    if (sl0 > 0){
        xm1 = xm[(size_t)(m0-1)*DI + d];
        xm2 = xm[(size_t)(m0-2)*DI + d];
        xm3 = xm[(size_t)(m0-3)*DI + d];
    }
    #pragma unroll 4
    for (int i=0;i<32;++i){
        float x0 = xm[(size_t)(m0+i)*DI + d];
        float acc = bb + w3*x0 + w2*xm1 + w1*xm2 + w0*xm3;
        float v = siluf_(acc);
        xc[(size_t)(m0+i)*DI + d] = v;
        sx[i*264 + d] = f2bf(v);
        xm3 = xm2; xm2 = xm1; xm1 = x0;
    }
    __syncthreads();
    // GEMM: 32x64(pad40) x K=256; wave w covers cols w*16
    int wv = d>>6, lane = d&63, q = lane>>4, r = lane&15;
    int n0 = wv*16;
    facc acc2[2] = {};
    const ushort* bp = wbx + ((size_t)j*64 + n0 + r)*256 + q*8;
    #pragma unroll
    for (int kb=0; kb<8; ++kb){
        bfrag a0 = *(bfrag*)&sx[r*264 + kb*32 + q*8];
        bfrag a1 = *(bfrag*)&sx[(r+16)*264 + kb*32 + q*8];
        bfrag b  = *(const bfrag*)(bp + kb*32);
        acc2[0] = __builtin_amdgcn_mfma_f32_16x16x32_bf16(a0,b,acc2[0],0,0,0);
        acc2[1] = __builtin_amdgcn_mfma_f32_16x16x32_bf16(a1,b,acc2[1],0,0,0);
    }
    int col = n0 + r;
    #pragma unroll
    for (int im=0; im<2; ++im){
        #pragma unroll
        for (int r2=0; r2<4; ++r2){
            int row = m0 + im*16 + q*4 + r2;
            float vv = acc2[im][r2];
            if      (col < 8)  dtr[(size_t)row*RK + col] = vv;
            else if (col < 24) Bc [(size_t)row*NS + (col-8)] = vv;
            else if (col < 40) Cc [(size_t)row*NS + (col-24)] = vv;
        }
    }
}

// ---------------- scan phase 1: fused dt_proj+softplus, per-chunk affine summaries
__global__ void k_scan1(const float* __restrict__ dtr, const float* __restrict__ xcv,
                        const float* __restrict__ Bc, const float* __restrict__ A_log,
                        const float* __restrict__ Wdt, const float* __restrict__ bdt,
                        float* __restrict__ Aprod, float* __restrict__ Bend, int blk){
    // grid (NC, NSTREAM), block 256 (d)
    int c = blockIdx.x, s = blockIdx.y; int j = (s>>1)*3 + blk;
    int d = threadIdx.x;
    __shared__ float sB[CHUNK*NS];     // 256
    __shared__ float sdtr[CHUNK*RK];   // 128
    int base_tok = s*L + c*CHUNK;
    sB[d] = Bc[(size_t)base_tok*NS + d];
    if (d < CHUNK*RK) sdtr[d] = dtr[(size_t)base_tok*RK + d];
    float A[NS];
    const float* ar = A_log + ((size_t)j*DI + d)*NS;
    #pragma unroll
    for (int n=0;n<NS;++n) A[n] = -__expf(ar[n]);
    float wv[RK];
    const float* wr = Wdt + ((size_t)j*DI + d)*RK;
    #pragma unroll
    for (int r=0;r<RK;++r) wv[r] = wr[r];
    float bb = bdt[j*DI + d];
    float ap[NS], hs[NS];
    #pragma unroll
    for (int n=0;n<NS;++n){ ap[n]=1.f; hs[n]=0.f; }
    __syncthreads();
    #pragma unroll 4
    for (int l=0;l<CHUNK;++l){
        int tb = base_tok + l;
        float t = bb;
        #pragma unroll
        for (int r=0;r<RK;++r) t += sdtr[l*RK+r]*wv[r];
        float dtv = softplusf_(t);
        float xv  = xcv[(size_t)tb*DI + d];
        float dbx = dtv*xv;
        #pragma unroll
        for (int n=0;n<NS;++n){
            float dA = __expf(dtv*A[n]);
            ap[n] *= dA;
            hs[n] = dA*hs[n] + dbx*sB[l*NS+n];
        }
    }
    size_t obase = ((size_t)(s*NC + c)*NS)*DI + d;
    #pragma unroll
    for (int n=0;n<NS;++n){
        Aprod[obase + (size_t)n*DI] = ap[n];
        Bend [obase + (size_t)n*DI] = hs[n];
    }
}

// ---------------- scan mid: fold chunk summaries; Bend becomes carry-in h0
__global__ void k_scanmid(const float* __restrict__ Aprod, float* __restrict__ Bend){
    // 128 blocks x 128: tid = s*4096 + n*256 + d
    int tid = blockIdx.x*128 + threadIdx.x;
    int s = tid >> 12;
    int nd = tid & 4095;
    const size_t stride = (size_t)NS*DI;
    size_t base = ((size_t)s*NC)*stride + nd;
    float h = 0.f;
    for (int c0=0; c0<NC; c0+=16){
        float a[16], b[16];
        #pragma unroll
        for (int i=0;i<16;++i){
            a[i] = Aprod[base + (size_t)(c0+i)*stride];
            b[i] = Bend [base + (size_t)(c0+i)*stride];
        }
        #pragma unroll
        for (int i=0;i<16;++i){
            Bend[base + (size_t)(c0+i)*stride] = h;  // carry INTO chunk c0+i
            h = a[i]*h + b[i];
        }
    }
}

// ---------------- FUSED scan phase 2 + gate + out_proj GEMM
// grid (NC, NSTREAM), block 256. Phase A: scan chunk (thread-per-d) -> g in LDS.
// Phase B: 16x128 GEMM (K=256) -> cur.
__global__ void k_scan2out(const float* __restrict__ dtr, const float* __restrict__ xcv,
                           const float* __restrict__ Bc, const float* __restrict__ Cc,
                           const float* __restrict__ A_log,
                           const float* __restrict__ Wdt, const float* __restrict__ bdt,
                           const float* __restrict__ h0, const float* __restrict__ z,
                           const float* __restrict__ Dp, const ushort* __restrict__ wbo,
                           float* __restrict__ cur, int blk){
    int c = blockIdx.x, s = blockIdx.y; int j = (s>>1)*3 + blk;
    int d = threadIdx.x;
    __shared__ float sB[CHUNK*NS], sC[CHUNK*NS], sdtr[CHUNK*RK];
    __shared__ ushort sg[CHUNK*264];   // 16 x 256 bf16, row stride 264
    int base_tok = s*L + c*CHUNK;
    sB[d] = Bc[(size_t)base_tok*NS + d];
    sC[d] = Cc[(size_t)base_tok*NS + d];
    if (d < CHUNK*RK) sdtr[d] = dtr[(size_t)base_tok*RK + d];
    float A[NS];
    const float* ar = A_log + ((size_t)j*DI + d)*NS;
    #pragma unroll
    for (int n=0;n<NS;++n) A[n] = -__expf(ar[n]);
    float wv[RK];
    const float* wr = Wdt + ((size_t)j*DI + d)*RK;
    #pragma unroll
    for (int r=0;r<RK;++r) wv[r] = wr[r];
    float bb = bdt[j*DI + d];
    float Dpd = Dp[j*DI + d];
    float hs[NS];
    size_t ibase = ((size_t)(s*NC + c)*NS)*DI + d;
    #pragma unroll
    for (int n=0;n<NS;++n) hs[n] = h0[ibase + (size_t)n*DI];
    __syncthreads();
    #pragma unroll 4
    for (int l=0;l<CHUNK;++l){
        int tb = base_tok + l;
        float t = bb;
        #pragma unroll
        for (int r=0;r<RK;++r) t += sdtr[l*RK+r]*wv[r];
        float dtv = softplusf_(t);
        float xv  = xcv[(size_t)tb*DI + d];
        float dbx = dtv*xv;
        float p = 0.f;
        #pragma unroll
        for (int n=0;n<NS;++n){
            float dA = __expf(dtv*A[n]);
            hs[n] = dA*hs[n] + dbx*sB[l*NS+n];
            p += hs[n]*sC[l*NS+n];
        }
        float zv = z[(size_t)tb*DI + d];
        sg[l*264 + d] = f2bf((p + Dpd*xv)*siluf_(zv));
    }
    __syncthreads();
    // Phase B: 16x128 GEMM; wave w covers cols w*32
    int wvi = d>>6, lane = d&63, q = lane>>4, r = lane&15;
    int n0 = wvi*32;
    facc acc[2] = {};
    const ushort* b0p = wbo + ((size_t)j*128 + n0 + r)*256 + q*8;
    const ushort* b1p = b0p + (size_t)16*256;
    #pragma unroll
    for (int kb=0; kb<8; ++kb){
        bfrag a  = *(bfrag*)&sg[r*264 + kb*32 + q*8];
        bfrag b0 = *(const bfrag*)(b0p + kb*32);
        bfrag b1 = *(const bfrag*)(b1p + kb*32);
        acc[0] = __builtin_amdgcn_mfma_f32_16x16x32_bf16(a,b0,acc[0],0,0,0);
        acc[1] = __builtin_amdgcn_mfma_f32_16x16x32_bf16(a,b1,acc[1],0,0,0);
    }
    #pragma unroll
    for (int in=0; in<2; ++in){
        int col = n0 + in*16 + r;
        #pragma unroll
        for (int r2=0; r2<4; ++r2){
            int row = q*4 + r2;   // token within chunk
            cur[(size_t)(base_tok+row)*D + col] = acc[in][r2];
        }
    }
}

// ---------------- final combine
__global__ void k_final(const float* __restrict__ cur, const float* __restrict__ res,
                        float* __restrict__ out){
    int l = blockIdx.x, b = blockIdx.y, d = threadIdx.x;
    int tf = (b*L + l)*D + d;
    int tbk = ((2+b)*L + (L-1-l))*D + d;
    float f  = cur[tf] + res[tf];
    float bw = cur[tbk] + res[tbk];
    out[((size_t)(b*D + d))*L + l] = f + bw;
    out[(size_t)2*D*L + (size_t)(b*L + l)*D + d] = res[tf];
    out[(size_t)2*D*L + (size_t)((2+b)*L + l)*D + d] = res[((2+b)*L + l)*D + d];
}

extern "C" void kernel_launch(void* const* d_in, const int* in_sizes, int n_in,
                              void* d_out, int out_size, void* d_ws, size_t ws_size,
                              hipStream_t stream){
    const float* x         = (const float*)d_in[0];
    const float* convd_w   = (const float*)d_in[1];
    const float* convd_b   = (const float*)d_in[2];
    const float* ln_w      = (const float*)d_in[3];
    const float* ln_b      = (const float*)d_in[4];
    const float* in_proj_w = (const float*)d_in[5];
    const float* conv_w    = (const float*)d_in[6];
    const float* conv_b    = (const float*)d_in[7];
    const float* xproj_w   = (const float*)d_in[8];
    const float* dtproj_w  = (const float*)d_in[9];
    const float* dtproj_b  = (const float*)d_in[10];
    const float* A_log     = (const float*)d_in[11];
    const float* Dparam    = (const float*)d_in[12];
    const float* outproj_w = (const float*)d_in[13];

    float* ws = (float*)d_ws;
    const size_t SZ_D  = (size_t)TOK*D;    // 1,048,576 floats
    const size_t SZ_DI = (size_t)TOK*DI;   // 2,097,152 floats
    float* h     = ws; ws += SZ_D;
    float* res0  = ws; ws += SZ_D;
    float* res1  = ws; ws += SZ_D;
    float* cur   = ws; ws += SZ_D;
    float* xm    = ws; ws += SZ_DI;
    float* z     = ws; ws += SZ_DI;
    float* xc    = ws; ws += SZ_DI;
    float* Aprod = ws; ws += SZ_DI;  // NSTREAM*NC*NS*DI = SZ_DI
    float* Bend  = ws; ws += SZ_DI;
    float* dtr   = ws; ws += (size_t)TOK*RK;
    float* Bc    = ws; ws += (size_t)TOK*NS;
    float* Cc    = ws; ws += (size_t)TOK*NS;
    ushort* xp   = (ushort*)ws; ws += SZ_D/2;   // 4096x256 bf16
    ushort* wall = (ushort*)ws;                 // packed bf16 weights
    ushort* wbd  = wall;                        // (128,256)       32768
    ushort* wbi  = wall + 32768;                // (6,512,128)    393216
    ushort* wbo  = wall + 425984;               // (6,128,256)    196608
    ushort* wbx  = wall + 622592;               // (6,64,256) pad  98304

    k_cvtall<<<2816, 256, 0, stream>>>(convd_w, in_proj_w, outproj_w, xproj_w, wall);

    k_patch<<<dim3(L/256, CIN, B), 256, 0, stream>>>(x, xp);
    k_gemm_down<<<dim3(64, 2), 256, 0, stream>>>(xp, wbd, convd_b, h);

    // res ping-pong: blk0 -> res0, blk1 -> res1, blk2 -> res0 (final reads res0)
    float* resin[3]  = { nullptr, res0, res1 };
    float* resout[3] = { res0,    res1, res0 };
    for (int blk = 0; blk < 3; ++blk){
        const float* ci = (blk==0) ? h : cur;
        const float* ri = (blk==0) ? h : resin[blk];   // dummy for blk0
        k_fused_in<<<dim3(TOK/64, 8), 256, 0, stream>>>(ci, ri, resout[blk], ln_w, ln_b,
                                                        wbi, xm, z, blk, blk==0);
        k_convx<<<TOK/32, 256, 0, stream>>>(xm, conv_w, conv_b, wbx, xc, dtr, Bc, Cc, blk);
        k_scan1<<<dim3(NC, NSTREAM), 256, 0, stream>>>(dtr, xc, Bc, A_log, dtproj_w, dtproj_b, Aprod, Bend, blk);
        k_scanmid<<<128, 128, 0, stream>>>(Aprod, Bend);
        k_scan2out<<<dim3(NC, NSTREAM), 256, 0, stream>>>(dtr, xc, Bc, Cc, A_log, dtproj_w, dtproj_b,
                                                          Bend, z, Dparam, wbo, cur, blk);
    }

    k_final<<<dim3(L, B), 128, 0, stream>>>(cur, res0, (float*)d_out);
}